// Round 11
// baseline (356.773 us; speedup 1.0000x reference)
//
#include <hip/hip_runtime.h>
#include <math.h>

// BS=128, L=256, D=512, H=2, DK=256.
// Conv branches dead (gather idx < 256). Split-bf16 MFMA GEMMs, all 2-phase
// __syncthreads-only (no manual barriers/vmcnt). A = Fq(Q(x)) via composed
// weight; V GEMM removed via x=(p@cap)@Wv^T+bv. Gate-shielding: A, G, kg-gemm
// 1-pass bf16; K 3-pass split. K-proj + A fused into one dispatch; softmax
// fused into pbar; pbar reads bf16 capHi.

typedef short bf16x8 __attribute__((ext_vector_type(8)));
typedef float f32x4 __attribute__((ext_vector_type(4)));
typedef short short4v __attribute__((ext_vector_type(4)));

__device__ __forceinline__ short f2bf(float x) {
    union { float f; unsigned u; } c; c.f = x;
    unsigned r = c.u + 0x7FFFu + ((c.u >> 16) & 1u);
    return (short)(r >> 16);
}
__device__ __forceinline__ float bf2f(short h) {
    union { float f; unsigned u; } c; c.u = ((unsigned)(unsigned short)h) << 16;
    return c.f;
}
__device__ __forceinline__ void glds16(const void* g, void* l) {
    __builtin_amdgcn_global_load_lds(
        (const __attribute__((address_space(1))) void*)g,
        (__attribute__((address_space(3))) void*)l, 16, 0, 0);
}

// ---------------- split fp32 -> bf16 hi/lo ----------------
struct SplitArgs {
    const float* src[4];
    short* hi[4];
    short* lo[4];
    int n4[4];
};
__global__ __launch_bounds__(256) void split_multi(SplitArgs a)
{
    const int j = blockIdx.y;
    const float4* s = (const float4*)a.src[j];
    short* hi = a.hi[j];
    short* lo = a.lo[j];
    const int n4 = a.n4[j];
    for (int i = blockIdx.x * 256 + threadIdx.x; i < n4; i += gridDim.x * 256) {
        float4 x = s[i];
        short4v h, l;
        h.x = f2bf(x.x); l.x = f2bf(x.x - bf2f(h.x));
        h.y = f2bf(x.y); l.y = f2bf(x.y - bf2f(h.y));
        h.z = f2bf(x.z); l.z = f2bf(x.z - bf2f(h.z));
        h.w = f2bf(x.w); l.w = f2bf(x.w - bf2f(h.w));
        *(short4v*)&hi[i * 4] = h;
        *(short4v*)&lo[i * 4] = l;
    }
}

// ---------------- composed weight Wa = Wfq @ Wq_h (bf16), ba = Wfq@bq_h + bfq ----
__global__ __launch_bounds__(256)
void compose(const float* __restrict__ Wq, const float* __restrict__ bq,
             const float* __restrict__ Wfq, const float* __restrict__ bfq,
             short* __restrict__ WaHi, float* __restrict__ ba)
{
    __shared__ float fq[256];
    __shared__ float redc[256];
    const int op = blockIdx.x;          // 0..511: h = op>>8, o = op&255
    const int h = op >> 8, o = op & 255;
    const int t = threadIdx.x;
    fq[t] = Wfq[o * 256 + t];
    redc[t] = fq[t] * bq[h * 256 + t];
    __syncthreads();
    for (int s = 128; s > 0; s >>= 1) {
        if (t < s) redc[t] += redc[t + s];
        __syncthreads();
    }
    if (t == 0) ba[op] = redc[0] + bfq[o];
    float s0 = 0.f, s1 = 0.f;
    for (int d = 0; d < 256; ++d) {
        const float f = fq[d];
        const float* wr = Wq + (size_t)(h * 256 + d) * 512;
        s0 += f * wr[t];
        s1 += f * wr[t + 256];
    }
    const size_t ro = (size_t)op * 512;
    WaHi[ro + t] = f2bf(s0);
    WaHi[ro + 256 + t] = f2bf(s1);
}

// ---------------- fused KA GEMM: K (3-pass split) + A (1-pass), 2-phase ----------------
// grid (8, 256); bn<512 -> K cols (split output), bn>=512 -> A cols (bf16).
__global__ __launch_bounds__(256, 2)
void gemm_ka(const short* __restrict__ capHi, const short* __restrict__ capLo,
             const short* __restrict__ WkHi, const short* __restrict__ WkLo,
             const short* __restrict__ WaHi,
             const float* __restrict__ bk, const float* __restrict__ ba,
             short* __restrict__ KAhi, short* __restrict__ KAlo)
{
    __shared__ short lds[2][16384];
    const int tid = threadIdx.x;
    const int bm = blockIdx.y * 128;
    const int bnx = blockIdx.x;
    const bool sp = bnx < 4;
    const int bn = bnx * 128;
    const int brow = sp ? bn : bn - 512;
    const short* Bh = sp ? WkHi : WaHi;

    const int lane = tid & 63;
    const int wr = (tid >> 7) & 1, wc = (tid >> 6) & 1;
    const int fr = lane & 15, kc = lane >> 4;
    const int r0 = tid >> 2;
    const int e0 = (((tid & 3) ^ ((r0 >> 1) & 3))) * 8;
    const int kce = (kc ^ ((fr >> 1) & 3)) * 8;

    auto stage = [&](int ph, int k0) {
        short* b = lds[ph];
        glds16(capHi + (size_t)(bm + r0) * 512 + k0 + e0,       b + tid * 8);
        glds16(capHi + (size_t)(bm + r0 + 64) * 512 + k0 + e0,  b + (tid + 256) * 8);
        glds16(Bh + (size_t)(brow + r0) * 512 + k0 + e0,        b + 4096 + tid * 8);
        glds16(Bh + (size_t)(brow + r0 + 64) * 512 + k0 + e0,   b + 4096 + (tid + 256) * 8);
        if (sp) {
            glds16(capLo + (size_t)(bm + r0) * 512 + k0 + e0,       b + 8192 + tid * 8);
            glds16(capLo + (size_t)(bm + r0 + 64) * 512 + k0 + e0,  b + 8192 + (tid + 256) * 8);
            glds16(WkLo + (size_t)(brow + r0) * 512 + k0 + e0,      b + 12288 + tid * 8);
            glds16(WkLo + (size_t)(brow + r0 + 64) * 512 + k0 + e0, b + 12288 + (tid + 256) * 8);
        }
    };

    f32x4 acc[4][4];
#pragma unroll
    for (int i = 0; i < 4; ++i)
#pragma unroll
        for (int j = 0; j < 4; ++j) acc[i][j] = (f32x4){0.f, 0.f, 0.f, 0.f};

    stage(0, 0);
    __syncthreads();
    for (int s = 0; s < 16; ++s) {
        if (s + 1 < 16) stage((s + 1) & 1, (s + 1) * 32);
        const short* b = lds[s & 1];
        bf16x8 ah[4], bh[4];
#pragma unroll
        for (int i = 0; i < 4; ++i)
            ah[i] = *(const bf16x8*)&b[(wr * 64 + i * 16 + fr) * 32 + kce];
#pragma unroll
        for (int i = 0; i < 4; ++i)
            bh[i] = *(const bf16x8*)&b[4096 + (wc * 64 + i * 16 + fr) * 32 + kce];
#pragma unroll
        for (int mi = 0; mi < 4; ++mi)
#pragma unroll
            for (int ni = 0; ni < 4; ++ni)
                acc[mi][ni] = __builtin_amdgcn_mfma_f32_16x16x32_bf16(ah[mi], bh[ni], acc[mi][ni], 0, 0, 0);
        if (sp) {
            bf16x8 al[4], bl[4];
#pragma unroll
            for (int i = 0; i < 4; ++i)
                al[i] = *(const bf16x8*)&b[8192 + (wr * 64 + i * 16 + fr) * 32 + kce];
#pragma unroll
            for (int mi = 0; mi < 4; ++mi)
#pragma unroll
                for (int ni = 0; ni < 4; ++ni)
                    acc[mi][ni] = __builtin_amdgcn_mfma_f32_16x16x32_bf16(al[mi], bh[ni], acc[mi][ni], 0, 0, 0);
#pragma unroll
            for (int i = 0; i < 4; ++i)
                bl[i] = *(const bf16x8*)&b[12288 + (wc * 64 + i * 16 + fr) * 32 + kce];
#pragma unroll
            for (int mi = 0; mi < 4; ++mi)
#pragma unroll
                for (int ni = 0; ni < 4; ++ni)
                    acc[mi][ni] = __builtin_amdgcn_mfma_f32_16x16x32_bf16(ah[mi], bl[ni], acc[mi][ni], 0, 0, 0);
        }
        __syncthreads();
    }

#pragma unroll
    for (int mi = 0; mi < 4; ++mi) {
#pragma unroll
        for (int ni = 0; ni < 4; ++ni) {
#pragma unroll
            for (int r = 0; r < 4; ++r) {
                const int row = bm + wr * 64 + mi * 16 + kc * 4 + r;
                const int colg = bn + wc * 64 + ni * 16 + fr;
                const float bb = sp ? bk[colg] : ba[colg - 512];
                const float v = acc[mi][ni][r] + bb;
                const size_t off = (size_t)row * 1024 + colg;
                if (sp) {
                    short h = f2bf(v);
                    KAhi[off] = h;
                    KAlo[off] = f2bf(v - bf2f(h));
                } else {
                    KAhi[off] = f2bf(v);
                }
            }
        }
    }
}

// ---------------- 1-pass 2-phase 128^2 GEMM for G and kg ----------------
// MODE 3: bf16 write of (acc+bias)*E1
// MODE 4: score partials from sigmoid(acc+bias)*(E1+E2)*qg
template<int MODE>
__global__ __launch_bounds__(256, 2)
void gemm2p(const short* __restrict__ Ahi, int lda, int aoff,
            const short* __restrict__ Bhi, int ldb,
            const float* __restrict__ bias,
            const short* __restrict__ E1, const short* __restrict__ E2,
            int ldep, int eoff,
            const float* __restrict__ qg, float* __restrict__ scorep,
            short* __restrict__ C0, int ldc, int coff, int K)
{
    __shared__ short lds[2][8192];
    __shared__ float sp[256];
    const int tid = threadIdx.x;
    const int bm = blockIdx.y * 128;
    const int bn = blockIdx.x * 128;
    const int z = blockIdx.z;
    const short* Ah = Ahi + (size_t)z * aoff;

    const int lane = tid & 63;
    const int wr = (tid >> 7) & 1, wc = (tid >> 6) & 1;
    const int fr = lane & 15, kc = lane >> 4;
    const int r0 = tid >> 2;
    const int e0 = (((tid & 3) ^ ((r0 >> 1) & 3))) * 8;
    const int kce = (kc ^ ((fr >> 1) & 3)) * 8;

    auto stage = [&](int ph, int k0) {
        short* b = lds[ph];
        glds16(Ah + (size_t)(bm + r0) * lda + k0 + e0,       b + tid * 8);
        glds16(Ah + (size_t)(bm + r0 + 64) * lda + k0 + e0,  b + (tid + 256) * 8);
        glds16(Bhi + (size_t)(bn + r0) * ldb + k0 + e0,      b + 4096 + tid * 8);
        glds16(Bhi + (size_t)(bn + r0 + 64) * ldb + k0 + e0, b + 4096 + (tid + 256) * 8);
    };

    f32x4 acc[4][4];
#pragma unroll
    for (int i = 0; i < 4; ++i)
#pragma unroll
        for (int j = 0; j < 4; ++j) acc[i][j] = (f32x4){0.f, 0.f, 0.f, 0.f};

    stage(0, 0);
    __syncthreads();
    const int NS = K / 32;
    for (int s = 0; s < NS; ++s) {
        if (s + 1 < NS) stage((s + 1) & 1, (s + 1) * 32);
        const short* b = lds[s & 1];
        bf16x8 ah[4], bh[4];
#pragma unroll
        for (int i = 0; i < 4; ++i)
            ah[i] = *(const bf16x8*)&b[(wr * 64 + i * 16 + fr) * 32 + kce];
#pragma unroll
        for (int i = 0; i < 4; ++i)
            bh[i] = *(const bf16x8*)&b[4096 + (wc * 64 + i * 16 + fr) * 32 + kce];
#pragma unroll
        for (int mi = 0; mi < 4; ++mi)
#pragma unroll
            for (int ni = 0; ni < 4; ++ni)
                acc[mi][ni] = __builtin_amdgcn_mfma_f32_16x16x32_bf16(ah[mi], bh[ni], acc[mi][ni], 0, 0, 0);
        __syncthreads();
    }

    float qgv[4];
    float pt[4][4];
    if (MODE == 4) {
        const int b = bm >> 8;
#pragma unroll
        for (int ni = 0; ni < 4; ++ni)
            qgv[ni] = qg[b * 512 + z * 256 + bn + wc * 64 + ni * 16 + fr];
#pragma unroll
        for (int mi = 0; mi < 4; ++mi)
#pragma unroll
            for (int r = 0; r < 4; ++r) pt[mi][r] = 0.f;
    }

#pragma unroll
    for (int mi = 0; mi < 4; ++mi) {
#pragma unroll
        for (int ni = 0; ni < 4; ++ni) {
#pragma unroll
            for (int r = 0; r < 4; ++r) {
                const int row = bm + wr * 64 + mi * 16 + kc * 4 + r;
                const int col = bn + wc * 64 + ni * 16 + fr;
                const float v = acc[mi][ni][r] + bias[col];
                const size_t eoffs = (size_t)row * ldep + (size_t)z * eoff + col;
                if (MODE == 3) {
                    const float e = bf2f(E1[eoffs]);
                    C0[(size_t)row * ldc + (size_t)z * coff + col] = f2bf(v * e);
                } else {
                    const float e = bf2f(E1[eoffs]) + bf2f(E2[eoffs]);
                    const float kgv = e / (1.f + expf(-v));
                    pt[mi][r] += kgv * qgv[ni];
                }
            }
        }
    }

    if (MODE == 4) {
#pragma unroll
        for (int mi = 0; mi < 4; ++mi) {
#pragma unroll
            for (int r = 0; r < 4; ++r) {
                float p = pt[mi][r];
                p += __shfl_xor(p, 1);
                p += __shfl_xor(p, 2);
                p += __shfl_xor(p, 4);
                p += __shfl_xor(p, 8);
                if (fr == 0) {
                    const int row_local = wr * 64 + mi * 16 + kc * 4 + r;
                    sp[row_local * 2 + wc] = p;
                }
            }
        }
        __syncthreads();
        if (tid < 128) {
            const int row = bm + tid;
            const float s = sp[tid * 2] + sp[tid * 2 + 1];
            const int b = row >> 8, j = row & 255;
            scorep[((size_t)(b * 2 + z) * 256 + j) * 2 + blockIdx.x] = s;
        }
    }
}

// ---------------- qg at gathered rows: Q fp32-exact from cap ----------------
__global__ __launch_bounds__(256)
void qg_kernel(const float* __restrict__ cap,
               const short* __restrict__ Gbuf,
               const float* __restrict__ Wq, const float* __restrict__ bq,
               const float* __restrict__ Wfg, const float* __restrict__ bfg,
               const int* __restrict__ lengths, float* __restrict__ qg)
{
    __shared__ float cr[512];
    __shared__ float gs[256];
    const int b = blockIdx.x >> 1, h = blockIdx.x & 1;
    const int t = threadIdx.x;
    int r = lengths[b] - 1;
    if (r < 0) r = 0;
    if (r > 255) r = 255;
    const size_t base = ((size_t)b * 256 + r) * 512;
    cr[t] = cap[base + t];
    cr[t + 256] = cap[base + 256 + t];
    gs[t] = bf2f(Gbuf[base + h * 256 + t]);
    __syncthreads();
    const float4* wq4 = (const float4*)(Wq + (size_t)(h * 256 + t) * 512);
    float q = 0.f;
    for (int k4 = 0; k4 < 128; ++k4) {
        float4 w = wq4[k4];
        q += w.x * cr[k4 * 4 + 0] + w.y * cr[k4 * 4 + 1]
           + w.z * cr[k4 * 4 + 2] + w.w * cr[k4 * 4 + 3];
    }
    q += bq[h * 256 + t];
    const float4* w4 = (const float4*)(Wfg + (size_t)t * 256);
    float a = 0.f;
    for (int k4 = 0; k4 < 64; ++k4) {
        float4 w = w4[k4];
        a += w.x * gs[k4 * 4 + 0] + w.y * gs[k4 * 4 + 1]
           + w.z * gs[k4 * 4 + 2] + w.w * gs[k4 * 4 + 3];
    }
    a += bfg[t];
    qg[b * 512 + h * 256 + t] = q / (1.f + expf(-a));
}

// ---------------- softmax (inline) + pbar from bf16 capHi ----------------
__global__ __launch_bounds__(256)
void pbar_kernel(const float* __restrict__ scorep, const short* __restrict__ capHi,
                 float* __restrict__ pbar)
{
    __shared__ float sc[512], red[512];
    const int b = blockIdx.y, cg = blockIdx.x;
    const int t = threadIdx.x;
#pragma unroll
    for (int i = 0; i < 2; ++i) {
        const int o = t + i * 256;
        const int h = o >> 8, j = o & 255;
        const size_t si = ((size_t)(b * 2 + h) * 256 + j) * 2;
        sc[o] = floorf((scorep[si] + scorep[si + 1]) * 0.0625f);
    }
    __syncthreads();
    red[t] = sc[t]; red[t + 256] = sc[t + 256];
    __syncthreads();
    for (int s = 128; s > 0; s >>= 1) {
        if (t < s) {
            red[t] = fmaxf(red[t], red[t + s]);
            red[256 + t] = fmaxf(red[256 + t], red[256 + t + s]);
        }
        __syncthreads();
    }
    const float mx0 = red[0], mx1 = red[256];
    __syncthreads();
    const float e0 = expf(sc[t] - mx0);
    const float e1 = expf(sc[t + 256] - mx1);
    red[t] = e0; red[t + 256] = e1;
    __syncthreads();
    for (int s = 128; s > 0; s >>= 1) {
        if (t < s) { red[t] += red[t + s]; red[256 + t] += red[256 + t + s]; }
        __syncthreads();
    }
    sc[t] = e0 / red[0];
    sc[t + 256] = e1 / red[256];
    __syncthreads();

    const int c = cg * 64 + (t & 63);
    const int jg = t >> 6;
    float a0 = 0.f, a1 = 0.f;
    for (int j = jg * 64; j < jg * 64 + 64; ++j) {
        const float cv = bf2f(capHi[((size_t)(b * 256 + j)) * 512 + c]);
        a0 += sc[j] * cv;
        a1 += sc[256 + j] * cv;
    }
    red[t] = a0;
    __syncthreads();
    if (t < 64) {
        const float s0 = red[t] + red[t + 64] + red[t + 128] + red[t + 192];
        pbar[b * 1024 + cg * 64 + t] = s0;
    }
    __syncthreads();
    red[t] = a1;
    __syncthreads();
    if (t < 64) {
        const float s1 = red[t] + red[t + 64] + red[t + 128] + red[t + 192];
        pbar[b * 1024 + 512 + cg * 64 + t] = s1;
    }
}

// ---------------- x = pbar@Wv^T + bv, BN1, residual ----------------
__global__ __launch_bounds__(256)
void bnx_kernel(const float* __restrict__ pbar, const float* __restrict__ cap,
                const int* __restrict__ lengths,
                const float* __restrict__ Wv, const float* __restrict__ bv,
                const float* __restrict__ g1, const float* __restrict__ b1,
                const float* __restrict__ m1, const float* __restrict__ v1,
                float* __restrict__ xga)
{
    __shared__ float pb[1024];
    const int b = blockIdx.x;
    const int t = threadIdx.x;
    int r = lengths[b] - 1;
    if (r < 0) r = 0;
    if (r > 255) r = 255;
    const size_t base = ((size_t)b * 256 + r) * 512;
    pb[t] = pbar[b * 1024 + t];
    pb[t + 256] = pbar[b * 1024 + 256 + t];
    pb[t + 512] = pbar[b * 1024 + 512 + t];
    pb[t + 768] = pbar[b * 1024 + 768 + t];
    __syncthreads();
    float x0 = 0.f, x1 = 0.f;
    {
        const float4* w4 = (const float4*)(Wv + (size_t)t * 512);
        for (int k4 = 0; k4 < 128; ++k4) {
            float4 w = w4[k4];
            x0 += w.x * pb[k4 * 4 + 0] + w.y * pb[k4 * 4 + 1]
                + w.z * pb[k4 * 4 + 2] + w.w * pb[k4 * 4 + 3];
        }
        x0 += bv[t];
    }
    {
        const float4* w4 = (const float4*)(Wv + (size_t)(t + 256) * 512);
        for (int k4 = 0; k4 < 128; ++k4) {
            float4 w = w4[k4];
            x1 += w.x * pb[512 + k4 * 4 + 0] + w.y * pb[512 + k4 * 4 + 1]
                + w.z * pb[512 + k4 * 4 + 2] + w.w * pb[512 + k4 * 4 + 3];
        }
        x1 += bv[t + 256];
    }
    const int c0 = t, c1 = t + 256;
    const float s0 = g1[c0] / sqrtf(v1[c0] + 1e-5f);
    const float s1 = g1[c1] / sqrtf(v1[c1] + 1e-5f);
    xga[b * 512 + c0] = cap[base + c0] + (x0 - m1[c0]) * s0 + b1[c0];
    xga[b * 512 + c1] = cap[base + c1] + (x1 - m1[c1]) * s1 + b1[c1];
}

// ---------------- MLP strip GEMMs (weights read once) ----------------
__global__ __launch_bounds__(256)
void mlp1(const float* __restrict__ xga, const float* __restrict__ W,
          const float* __restrict__ bias, float* __restrict__ hid)
{
    __shared__ float xs[16 * 512];
    const int r0 = blockIdx.y * 16;
    const int c0 = blockIdx.x * 64;
    for (int i = threadIdx.x; i < 2048; i += 256)
        ((float4*)xs)[i] = ((const float4*)(xga + (size_t)r0 * 512))[i];
    __syncthreads();
    const int col = c0 + (threadIdx.x & 63);
    const int rg = (threadIdx.x >> 6) * 4;
    float acc[4] = {0.f, 0.f, 0.f, 0.f};
    const float4* w4 = (const float4*)(W + (size_t)col * 512);
    for (int k4 = 0; k4 < 128; ++k4) {
        float4 w = w4[k4];
#pragma unroll
        for (int rr = 0; rr < 4; ++rr) {
            float4 x = *(const float4*)&xs[(rg + rr) * 512 + k4 * 4];
            acc[rr] += w.x * x.x + w.y * x.y + w.z * x.z + w.w * x.w;
        }
    }
    const float bb = bias[col];
#pragma unroll
    for (int rr = 0; rr < 4; ++rr)
        hid[(size_t)(r0 + rg + rr) * 1024 + col] = fmaxf(acc[rr] + bb, 0.f);
}

__global__ __launch_bounds__(256)
void mlp2(const float* __restrict__ hid, const float* __restrict__ W,
          const float* __restrict__ bias, const float* __restrict__ xga,
          float* __restrict__ tex)
{
    __shared__ float xs[16 * 1024];
    const int r0 = blockIdx.y * 16;
    const int c0 = blockIdx.x * 64;
    for (int i = threadIdx.x; i < 4096; i += 256)
        ((float4*)xs)[i] = ((const float4*)(hid + (size_t)r0 * 1024))[i];
    __syncthreads();
    const int col = c0 + (threadIdx.x & 63);
    const int rg = (threadIdx.x >> 6) * 4;
    float acc[4] = {0.f, 0.f, 0.f, 0.f};
    const float4* w4 = (const float4*)(W + (size_t)col * 1024);
    for (int k4 = 0; k4 < 256; ++k4) {
        float4 w = w4[k4];
#pragma unroll
        for (int rr = 0; rr < 4; ++rr) {
            float4 x = *(const float4*)&xs[(rg + rr) * 1024 + k4 * 4];
            acc[rr] += w.x * x.x + w.y * x.y + w.z * x.z + w.w * x.w;
        }
    }
    const float bb = bias[col];
#pragma unroll
    for (int rr = 0; rr < 4; ++rr) {
        const int row = r0 + rg + rr;
        tex[(size_t)row * 512 + col] = acc[rr] + bb + xga[(size_t)row * 512 + col];
    }
}

__global__ __launch_bounds__(256)
void norm_out(const float* __restrict__ tex, float* __restrict__ out)
{
    __shared__ float red[256];
    const int b = blockIdx.x;
    const int t = threadIdx.x;
    const float a = tex[b * 512 + t];
    const float c = tex[b * 512 + 256 + t];
    red[t] = a * a + c * c;
    __syncthreads();
    for (int s = 128; s > 0; s >>= 1) {
        if (t < s) red[t] += red[t + s];
        __syncthreads();
    }
    const float inv = 1.f / (sqrtf(red[0]) + 1e-8f);
    out[b * 512 + t] = a * inv;
    out[b * 512 + 256 + t] = c * inv;
}

extern "C" void kernel_launch(void* const* d_in, const int* in_sizes, int n_in,
                              void* d_out, int out_size, void* d_ws, size_t ws_size,
                              hipStream_t stream)
{
    const float* cap = (const float*)d_in[0];
    const int* lengths = (const int*)d_in[1];
    const float* Wq  = (const float*)d_in[2];
    const float* Wk  = (const float*)d_in[3];
    const float* Wv  = (const float*)d_in[4];
    const float* bq  = (const float*)d_in[5];
    const float* bk  = (const float*)d_in[6];
    const float* bv  = (const float*)d_in[7];
    const float* Wfq = (const float*)d_in[8];
    const float* bfq = (const float*)d_in[9];
    const float* Wfk = (const float*)d_in[10];
    const float* bfk = (const float*)d_in[11];
    const float* Wfg = (const float*)d_in[12];
    const float* bfg = (const float*)d_in[13];
    const float* g1  = (const float*)d_in[14];
    const float* b1  = (const float*)d_in[15];
    const float* m1  = (const float*)d_in[16];
    const float* v1  = (const float*)d_in[17];
    const float* Wm1 = (const float*)d_in[30];
    const float* bm1 = (const float*)d_in[31];
    const float* Wm2 = (const float*)d_in[32];
    const float* bm2 = (const float*)d_in[33];
    float* out = (float*)d_out;

    char* w = (char*)d_ws;
    const size_t MB = 1024 * 1024;
    short* capHi = (short*)(w);                // 32MB (stays valid; pbar reads it)
    short* capLo = (short*)(w + 32 * MB);      // 32MB
    short* KAhi  = (short*)(w + 64 * MB);      // 64MB  [32768,1024]: 0-511 K, 512-1023 A
    short* KAlo  = (short*)(w + 128 * MB);     // 64MB  (only K-half written/used)
    short* Gbuf  = (short*)(w + 192 * MB);     // 32MB  [32768,512] bf16
    char* wp = w + 224 * MB;
    short* WkHi  = (short*)wp; wp += 524288;   // [512,512]
    short* WkLo  = (short*)wp; wp += 524288;
    short* WaHi  = (short*)wp; wp += 524288;   // [512,512] composed
    short* WfkHi = (short*)wp; wp += 131072;
    short* WfkLo = (short*)wp; wp += 131072;   // written, unused
    short* Wfg2Hi = (short*)wp; wp += 131072;
    short* Wfg2Lo = (short*)wp; wp += 131072;  // written, unused
    float* ba     = (float*)wp; wp += 2048;
    float* qg     = (float*)wp; wp += 262144;
    float* scorep = (float*)wp; wp += 524288;   // [128][2][256][2]
    float* pbar   = (float*)wp; wp += 524288;
    float* xga    = (float*)wp; wp += 262144;
    float* hid    = (float*)wp; wp += 524288;
    float* tex    = (float*)wp; wp += 262144;

    // 1. splits: cap, Wk, Wfk, Wfg2
    SplitArgs sa;
    sa.src[0] = cap;          sa.hi[0] = capHi;  sa.lo[0] = capLo;  sa.n4[0] = 4194304;
    sa.src[1] = Wk;           sa.hi[1] = WkHi;   sa.lo[1] = WkLo;   sa.n4[1] = 65536;
    sa.src[2] = Wfk;          sa.hi[2] = WfkHi;  sa.lo[2] = WfkLo;  sa.n4[2] = 16384;
    sa.src[3] = Wfg + 65536;  sa.hi[3] = Wfg2Hi; sa.lo[3] = Wfg2Lo; sa.n4[3] = 16384;
    split_multi<<<dim3(4096, 4), 256, 0, stream>>>(sa);

    // 2. composed Wa (bf16), ba
    compose<<<dim3(512), 256, 0, stream>>>(Wq, bq, Wfq, bfq, WaHi, ba);

    // 3. fused K (3-pass split) + A (1-pass) -> KA [32768,1024]
    gemm_ka<<<dim3(8, 256), 256, 0, stream>>>(capHi, capLo, WkHi, WkLo, WaHi,
                                              bk, ba, KAhi, KAlo);

    // 4. G = (K_h Wfk^T + bfk) * A : 1-pass bf16 -> Gbuf
    gemm2p<3><<<dim3(2, 256, 2), 256, 0, stream>>>(
        KAhi, 1024, 256, WfkHi, 256, bfk,
        KAhi + 512, nullptr, 1024, 256, nullptr, nullptr,
        Gbuf, 512, 256, 256);

    // 5. qg at gathered rows (Q fp32 from cap)
    qg_kernel<<<dim3(256), 256, 0, stream>>>(cap, Gbuf, Wq, bq, Wfg, bfg, lengths, qg);

    // 6. kg gemm + fused score partials (1-pass gemm; K read split)
    gemm2p<4><<<dim3(2, 256, 2), 256, 0, stream>>>(
        Gbuf, 512, 256, Wfg2Hi, 256, bfg + 256,
        KAhi, KAlo, 1024, 256, qg, scorep,
        nullptr, 0, 0, 256);

    // 7-8. softmax+pbar (bf16 cap), BN/residual
    pbar_kernel<<<dim3(8, 128), 256, 0, stream>>>(scorep, capHi, pbar);
    bnx_kernel<<<dim3(128), 256, 0, stream>>>(pbar, cap, lengths, Wv, bv, g1, b1, m1, v1, xga);

    // 9-11. MLP, norm
    mlp1<<<dim3(16, 8), 256, 0, stream>>>(xga, Wm1, bm1, hid);
    mlp2<<<dim3(8, 8), 256, 0, stream>>>(hid, Wm2, bm2, xga, tex);
    norm_out<<<dim3(128), 256, 0, stream>>>(tex, out);
}

// Round 12
// 334.104 us; speedup vs baseline: 1.0678x; 1.0678x over previous
//
#include <hip/hip_runtime.h>
#include <math.h>

// BS=128, L=256, D=512, H=2, DK=256.
// Conv branches dead (gather idx < 256). Split-bf16 MFMA GEMMs, all 2-phase
// __syncthreads-only (no manual barriers/vmcnt). A = Fq(Q(x)) via composed
// weight; V GEMM removed via x=(p@cap)@Wv^T+bv. Gate-shielding: A, G, kg-gemm
// 1-pass bf16; K 3-pass split. Separate uniform-work dispatches (fused KA
// regressed: heterogeneous blocks -> load imbalance). softmax fused into
// pbar; pbar reads bf16 capHi.

typedef short bf16x8 __attribute__((ext_vector_type(8)));
typedef float f32x4 __attribute__((ext_vector_type(4)));
typedef short short4v __attribute__((ext_vector_type(4)));

__device__ __forceinline__ short f2bf(float x) {
    union { float f; unsigned u; } c; c.f = x;
    unsigned r = c.u + 0x7FFFu + ((c.u >> 16) & 1u);
    return (short)(r >> 16);
}
__device__ __forceinline__ float bf2f(short h) {
    union { float f; unsigned u; } c; c.u = ((unsigned)(unsigned short)h) << 16;
    return c.f;
}
__device__ __forceinline__ void glds16(const void* g, void* l) {
    __builtin_amdgcn_global_load_lds(
        (const __attribute__((address_space(1))) void*)g,
        (__attribute__((address_space(3))) void*)l, 16, 0, 0);
}

// ---------------- split fp32 -> bf16 hi/lo ----------------
struct SplitArgs {
    const float* src[4];
    short* hi[4];
    short* lo[4];
    int n4[4];
};
__global__ __launch_bounds__(256) void split_multi(SplitArgs a)
{
    const int j = blockIdx.y;
    const float4* s = (const float4*)a.src[j];
    short* hi = a.hi[j];
    short* lo = a.lo[j];
    const int n4 = a.n4[j];
    for (int i = blockIdx.x * 256 + threadIdx.x; i < n4; i += gridDim.x * 256) {
        float4 x = s[i];
        short4v h, l;
        h.x = f2bf(x.x); l.x = f2bf(x.x - bf2f(h.x));
        h.y = f2bf(x.y); l.y = f2bf(x.y - bf2f(h.y));
        h.z = f2bf(x.z); l.z = f2bf(x.z - bf2f(h.z));
        h.w = f2bf(x.w); l.w = f2bf(x.w - bf2f(h.w));
        *(short4v*)&hi[i * 4] = h;
        *(short4v*)&lo[i * 4] = l;
    }
}

// ---------------- composed weight Wa = Wfq @ Wq_h (bf16), ba = Wfq@bq_h + bfq ----
__global__ __launch_bounds__(256)
void compose(const float* __restrict__ Wq, const float* __restrict__ bq,
             const float* __restrict__ Wfq, const float* __restrict__ bfq,
             short* __restrict__ WaHi, float* __restrict__ ba)
{
    __shared__ float fq[256];
    __shared__ float redc[256];
    const int op = blockIdx.x;          // 0..511: h = op>>8, o = op&255
    const int h = op >> 8, o = op & 255;
    const int t = threadIdx.x;
    fq[t] = Wfq[o * 256 + t];
    redc[t] = fq[t] * bq[h * 256 + t];
    __syncthreads();
    for (int s = 128; s > 0; s >>= 1) {
        if (t < s) redc[t] += redc[t + s];
        __syncthreads();
    }
    if (t == 0) ba[op] = redc[0] + bfq[o];
    float s0 = 0.f, s1 = 0.f;
    for (int d = 0; d < 256; ++d) {
        const float f = fq[d];
        const float* wr = Wq + (size_t)(h * 256 + d) * 512;
        s0 += f * wr[t];
        s1 += f * wr[t + 256];
    }
    const size_t ro = (size_t)op * 512;
    WaHi[ro + t] = f2bf(s0);
    WaHi[ro + 256 + t] = f2bf(s1);
}

// ---------------- 2-phase 128^2 GEMM, __syncthreads-only ----------------
// NSPLIT 3: virtual passes hi*hi + lo*hi + hi*lo (all staged per chunk).
// MODE 1: split write (C0,C1)     MODE 2: bf16 write (C0)
// MODE 3: bf16 write of (acc+bias)*E1
// MODE 4: score partials from sigmoid(acc+bias)*(E1+E2)*qg
template<int NSPLIT, int MODE>
__global__ __launch_bounds__(256, 2)
void gemm2p(const short* __restrict__ Ahi, const short* __restrict__ Alo,
            int lda, int aoff,
            const short* __restrict__ Bhi, const short* __restrict__ Blo, int ldb,
            const float* __restrict__ bias,
            const short* __restrict__ E1, const short* __restrict__ E2,
            int ldep, int eoff,
            const float* __restrict__ qg, float* __restrict__ scorep,
            short* __restrict__ C0, short* __restrict__ C1,
            int ldc, int coff, int K)
{
    constexpr int SLOT = (NSPLIT == 3) ? 16384 : 8192;
    __shared__ short lds[2][SLOT];
    __shared__ float sp[256];
    const int tid = threadIdx.x;
    const int bm = blockIdx.y * 128;
    const int bn = blockIdx.x * 128;
    const int z = blockIdx.z;
    const short* Ah = Ahi + (size_t)z * aoff;
    const short* Al = (NSPLIT == 3) ? (Alo + (size_t)z * aoff) : nullptr;

    const int lane = tid & 63;
    const int wr = (tid >> 7) & 1, wc = (tid >> 6) & 1;
    const int fr = lane & 15, kc = lane >> 4;
    const int r0 = tid >> 2;
    const int e0 = (((tid & 3) ^ ((r0 >> 1) & 3))) * 8;   // pre-swizzled source
    const int kce = (kc ^ ((fr >> 1) & 3)) * 8;           // read-side swizzle

    auto stage = [&](int ph, int k0) {
        short* b = lds[ph];
        glds16(Ah + (size_t)(bm + r0) * lda + k0 + e0,       b + tid * 8);
        glds16(Ah + (size_t)(bm + r0 + 64) * lda + k0 + e0,  b + (tid + 256) * 8);
        glds16(Bhi + (size_t)(bn + r0) * ldb + k0 + e0,      b + 4096 + tid * 8);
        glds16(Bhi + (size_t)(bn + r0 + 64) * ldb + k0 + e0, b + 4096 + (tid + 256) * 8);
        if constexpr (NSPLIT == 3) {
            glds16(Al + (size_t)(bm + r0) * lda + k0 + e0,       b + 8192 + tid * 8);
            glds16(Al + (size_t)(bm + r0 + 64) * lda + k0 + e0,  b + 8192 + (tid + 256) * 8);
            glds16(Blo + (size_t)(bn + r0) * ldb + k0 + e0,      b + 12288 + tid * 8);
            glds16(Blo + (size_t)(bn + r0 + 64) * ldb + k0 + e0, b + 12288 + (tid + 256) * 8);
        }
    };

    f32x4 acc[4][4];
#pragma unroll
    for (int i = 0; i < 4; ++i)
#pragma unroll
        for (int j = 0; j < 4; ++j) acc[i][j] = (f32x4){0.f, 0.f, 0.f, 0.f};

    stage(0, 0);
    __syncthreads();
    const int NS = K / 32;
    for (int s = 0; s < NS; ++s) {
        if (s + 1 < NS) stage((s + 1) & 1, (s + 1) * 32);
        const short* b = lds[s & 1];
        bf16x8 ah[4], bh[4];
#pragma unroll
        for (int i = 0; i < 4; ++i)
            ah[i] = *(const bf16x8*)&b[(wr * 64 + i * 16 + fr) * 32 + kce];
#pragma unroll
        for (int i = 0; i < 4; ++i)
            bh[i] = *(const bf16x8*)&b[4096 + (wc * 64 + i * 16 + fr) * 32 + kce];
#pragma unroll
        for (int mi = 0; mi < 4; ++mi)
#pragma unroll
            for (int ni = 0; ni < 4; ++ni)
                acc[mi][ni] = __builtin_amdgcn_mfma_f32_16x16x32_bf16(ah[mi], bh[ni], acc[mi][ni], 0, 0, 0);
        if constexpr (NSPLIT == 3) {
            bf16x8 al[4], bl[4];
#pragma unroll
            for (int i = 0; i < 4; ++i)
                al[i] = *(const bf16x8*)&b[8192 + (wr * 64 + i * 16 + fr) * 32 + kce];
#pragma unroll
            for (int mi = 0; mi < 4; ++mi)
#pragma unroll
                for (int ni = 0; ni < 4; ++ni)
                    acc[mi][ni] = __builtin_amdgcn_mfma_f32_16x16x32_bf16(al[mi], bh[ni], acc[mi][ni], 0, 0, 0);
#pragma unroll
            for (int i = 0; i < 4; ++i)
                bl[i] = *(const bf16x8*)&b[12288 + (wc * 64 + i * 16 + fr) * 32 + kce];
#pragma unroll
            for (int mi = 0; mi < 4; ++mi)
#pragma unroll
                for (int ni = 0; ni < 4; ++ni)
                    acc[mi][ni] = __builtin_amdgcn_mfma_f32_16x16x32_bf16(ah[mi], bl[ni], acc[mi][ni], 0, 0, 0);
        }
        __syncthreads();
    }

    float qgv[4];
    float pt[4][4];
    if (MODE == 4) {
        const int b = bm >> 8;
#pragma unroll
        for (int ni = 0; ni < 4; ++ni)
            qgv[ni] = qg[b * 512 + z * 256 + bn + wc * 64 + ni * 16 + fr];
#pragma unroll
        for (int mi = 0; mi < 4; ++mi)
#pragma unroll
            for (int r = 0; r < 4; ++r) pt[mi][r] = 0.f;
    }

#pragma unroll
    for (int mi = 0; mi < 4; ++mi) {
#pragma unroll
        for (int ni = 0; ni < 4; ++ni) {
#pragma unroll
            for (int r = 0; r < 4; ++r) {
                const int row = bm + wr * 64 + mi * 16 + kc * 4 + r;
                const int col = bn + wc * 64 + ni * 16 + fr;
                const float v = acc[mi][ni][r] + bias[col];
                if (MODE == 1) {
                    const size_t off = (size_t)row * ldc + (size_t)z * coff + col;
                    short h = f2bf(v);
                    C0[off] = h;
                    C1[off] = f2bf(v - bf2f(h));
                } else if (MODE == 2) {
                    C0[(size_t)row * ldc + (size_t)z * coff + col] = f2bf(v);
                } else if (MODE == 3) {
                    const size_t eoffs = (size_t)row * ldep + (size_t)z * eoff + col;
                    const float e = bf2f(E1[eoffs]);
                    C0[(size_t)row * ldc + (size_t)z * coff + col] = f2bf(v * e);
                } else if (MODE == 4) {
                    const size_t eoffs = (size_t)row * ldep + (size_t)z * eoff + col;
                    const float e = bf2f(E1[eoffs]) + bf2f(E2[eoffs]);
                    const float kgv = e / (1.f + expf(-v));
                    pt[mi][r] += kgv * qgv[ni];
                }
            }
        }
    }

    if (MODE == 4) {
#pragma unroll
        for (int mi = 0; mi < 4; ++mi) {
#pragma unroll
            for (int r = 0; r < 4; ++r) {
                float p = pt[mi][r];
                p += __shfl_xor(p, 1);
                p += __shfl_xor(p, 2);
                p += __shfl_xor(p, 4);
                p += __shfl_xor(p, 8);
                if (fr == 0) {
                    const int row_local = wr * 64 + mi * 16 + kc * 4 + r;
                    sp[row_local * 2 + wc] = p;
                }
            }
        }
        __syncthreads();
        if (tid < 128) {
            const int row = bm + tid;
            const float s = sp[tid * 2] + sp[tid * 2 + 1];
            const int b = row >> 8, j = row & 255;
            scorep[((size_t)(b * 2 + z) * 256 + j) * 2 + blockIdx.x] = s;
        }
    }
}

// ---------------- qg at gathered rows: Q fp32-exact from cap ----------------
__global__ __launch_bounds__(256)
void qg_kernel(const float* __restrict__ cap,
               const short* __restrict__ Gbuf,
               const float* __restrict__ Wq, const float* __restrict__ bq,
               const float* __restrict__ Wfg, const float* __restrict__ bfg,
               const int* __restrict__ lengths, float* __restrict__ qg)
{
    __shared__ float cr[512];
    __shared__ float gs[256];
    const int b = blockIdx.x >> 1, h = blockIdx.x & 1;
    const int t = threadIdx.x;
    int r = lengths[b] - 1;
    if (r < 0) r = 0;
    if (r > 255) r = 255;
    const size_t base = ((size_t)b * 256 + r) * 512;
    cr[t] = cap[base + t];
    cr[t + 256] = cap[base + 256 + t];
    gs[t] = bf2f(Gbuf[base + h * 256 + t]);
    __syncthreads();
    const float4* wq4 = (const float4*)(Wq + (size_t)(h * 256 + t) * 512);
    float q = 0.f;
    for (int k4 = 0; k4 < 128; ++k4) {
        float4 w = wq4[k4];
        q += w.x * cr[k4 * 4 + 0] + w.y * cr[k4 * 4 + 1]
           + w.z * cr[k4 * 4 + 2] + w.w * cr[k4 * 4 + 3];
    }
    q += bq[h * 256 + t];
    const float4* w4 = (const float4*)(Wfg + (size_t)t * 256);
    float a = 0.f;
    for (int k4 = 0; k4 < 64; ++k4) {
        float4 w = w4[k4];
        a += w.x * gs[k4 * 4 + 0] + w.y * gs[k4 * 4 + 1]
           + w.z * gs[k4 * 4 + 2] + w.w * gs[k4 * 4 + 3];
    }
    a += bfg[t];
    qg[b * 512 + h * 256 + t] = q / (1.f + expf(-a));
}

// ---------------- softmax (inline) + pbar from bf16 capHi ----------------
__global__ __launch_bounds__(256)
void pbar_kernel(const float* __restrict__ scorep, const short* __restrict__ capHi,
                 float* __restrict__ pbar)
{
    __shared__ float sc[512], red[512];
    const int b = blockIdx.y, cg = blockIdx.x;
    const int t = threadIdx.x;
#pragma unroll
    for (int i = 0; i < 2; ++i) {
        const int o = t + i * 256;
        const int h = o >> 8, j = o & 255;
        const size_t si = ((size_t)(b * 2 + h) * 256 + j) * 2;
        sc[o] = floorf((scorep[si] + scorep[si + 1]) * 0.0625f);
    }
    __syncthreads();
    red[t] = sc[t]; red[t + 256] = sc[t + 256];
    __syncthreads();
    for (int s = 128; s > 0; s >>= 1) {
        if (t < s) {
            red[t] = fmaxf(red[t], red[t + s]);
            red[256 + t] = fmaxf(red[256 + t], red[256 + t + s]);
        }
        __syncthreads();
    }
    const float mx0 = red[0], mx1 = red[256];
    __syncthreads();
    const float e0 = expf(sc[t] - mx0);
    const float e1 = expf(sc[t + 256] - mx1);
    red[t] = e0; red[t + 256] = e1;
    __syncthreads();
    for (int s = 128; s > 0; s >>= 1) {
        if (t < s) { red[t] += red[t + s]; red[256 + t] += red[256 + t + s]; }
        __syncthreads();
    }
    sc[t] = e0 / red[0];
    sc[t + 256] = e1 / red[256];
    __syncthreads();

    const int c = cg * 64 + (t & 63);
    const int jg = t >> 6;
    float a0 = 0.f, a1 = 0.f;
    for (int j = jg * 64; j < jg * 64 + 64; ++j) {
        const float cv = bf2f(capHi[((size_t)(b * 256 + j)) * 512 + c]);
        a0 += sc[j] * cv;
        a1 += sc[256 + j] * cv;
    }
    red[t] = a0;
    __syncthreads();
    if (t < 64) {
        const float s0 = red[t] + red[t + 64] + red[t + 128] + red[t + 192];
        pbar[b * 1024 + cg * 64 + t] = s0;
    }
    __syncthreads();
    red[t] = a1;
    __syncthreads();
    if (t < 64) {
        const float s1 = red[t] + red[t + 64] + red[t + 128] + red[t + 192];
        pbar[b * 1024 + 512 + cg * 64 + t] = s1;
    }
}

// ---------------- x = pbar@Wv^T + bv, BN1, residual ----------------
__global__ __launch_bounds__(256)
void bnx_kernel(const float* __restrict__ pbar, const float* __restrict__ cap,
                const int* __restrict__ lengths,
                const float* __restrict__ Wv, const float* __restrict__ bv,
                const float* __restrict__ g1, const float* __restrict__ b1,
                const float* __restrict__ m1, const float* __restrict__ v1,
                float* __restrict__ xga)
{
    __shared__ float pb[1024];
    const int b = blockIdx.x;
    const int t = threadIdx.x;
    int r = lengths[b] - 1;
    if (r < 0) r = 0;
    if (r > 255) r = 255;
    const size_t base = ((size_t)b * 256 + r) * 512;
    pb[t] = pbar[b * 1024 + t];
    pb[t + 256] = pbar[b * 1024 + 256 + t];
    pb[t + 512] = pbar[b * 1024 + 512 + t];
    pb[t + 768] = pbar[b * 1024 + 768 + t];
    __syncthreads();
    float x0 = 0.f, x1 = 0.f;
    {
        const float4* w4 = (const float4*)(Wv + (size_t)t * 512);
        for (int k4 = 0; k4 < 128; ++k4) {
            float4 w = w4[k4];
            x0 += w.x * pb[k4 * 4 + 0] + w.y * pb[k4 * 4 + 1]
                + w.z * pb[k4 * 4 + 2] + w.w * pb[k4 * 4 + 3];
        }
        x0 += bv[t];
    }
    {
        const float4* w4 = (const float4*)(Wv + (size_t)(t + 256) * 512);
        for (int k4 = 0; k4 < 128; ++k4) {
            float4 w = w4[k4];
            x1 += w.x * pb[512 + k4 * 4 + 0] + w.y * pb[512 + k4 * 4 + 1]
                + w.z * pb[512 + k4 * 4 + 2] + w.w * pb[512 + k4 * 4 + 3];
        }
        x1 += bv[t + 256];
    }
    const int c0 = t, c1 = t + 256;
    const float s0 = g1[c0] / sqrtf(v1[c0] + 1e-5f);
    const float s1 = g1[c1] / sqrtf(v1[c1] + 1e-5f);
    xga[b * 512 + c0] = cap[base + c0] + (x0 - m1[c0]) * s0 + b1[c0];
    xga[b * 512 + c1] = cap[base + c1] + (x1 - m1[c1]) * s1 + b1[c1];
}

// ---------------- MLP strip GEMMs (weights read once) ----------------
__global__ __launch_bounds__(256)
void mlp1(const float* __restrict__ xga, const float* __restrict__ W,
          const float* __restrict__ bias, float* __restrict__ hid)
{
    __shared__ float xs[16 * 512];
    const int r0 = blockIdx.y * 16;
    const int c0 = blockIdx.x * 64;
    for (int i = threadIdx.x; i < 2048; i += 256)
        ((float4*)xs)[i] = ((const float4*)(xga + (size_t)r0 * 512))[i];
    __syncthreads();
    const int col = c0 + (threadIdx.x & 63);
    const int rg = (threadIdx.x >> 6) * 4;
    float acc[4] = {0.f, 0.f, 0.f, 0.f};
    const float4* w4 = (const float4*)(W + (size_t)col * 512);
    for (int k4 = 0; k4 < 128; ++k4) {
        float4 w = w4[k4];
#pragma unroll
        for (int rr = 0; rr < 4; ++rr) {
            float4 x = *(const float4*)&xs[(rg + rr) * 512 + k4 * 4];
            acc[rr] += w.x * x.x + w.y * x.y + w.z * x.z + w.w * x.w;
        }
    }
    const float bb = bias[col];
#pragma unroll
    for (int rr = 0; rr < 4; ++rr)
        hid[(size_t)(r0 + rg + rr) * 1024 + col] = fmaxf(acc[rr] + bb, 0.f);
}

__global__ __launch_bounds__(256)
void mlp2(const float* __restrict__ hid, const float* __restrict__ W,
          const float* __restrict__ bias, const float* __restrict__ xga,
          float* __restrict__ tex)
{
    __shared__ float xs[16 * 1024];
    const int r0 = blockIdx.y * 16;
    const int c0 = blockIdx.x * 64;
    for (int i = threadIdx.x; i < 4096; i += 256)
        ((float4*)xs)[i] = ((const float4*)(hid + (size_t)r0 * 1024))[i];
    __syncthreads();
    const int col = c0 + (threadIdx.x & 63);
    const int rg = (threadIdx.x >> 6) * 4;
    float acc[4] = {0.f, 0.f, 0.f, 0.f};
    const float4* w4 = (const float4*)(W + (size_t)col * 1024);
    for (int k4 = 0; k4 < 256; ++k4) {
        float4 w = w4[k4];
#pragma unroll
        for (int rr = 0; rr < 4; ++rr) {
            float4 x = *(const float4*)&xs[(rg + rr) * 1024 + k4 * 4];
            acc[rr] += w.x * x.x + w.y * x.y + w.z * x.z + w.w * x.w;
        }
    }
    const float bb = bias[col];
#pragma unroll
    for (int rr = 0; rr < 4; ++rr) {
        const int row = r0 + rg + rr;
        tex[(size_t)row * 512 + col] = acc[rr] + bb + xga[(size_t)row * 512 + col];
    }
}

__global__ __launch_bounds__(256)
void norm_out(const float* __restrict__ tex, float* __restrict__ out)
{
    __shared__ float red[256];
    const int b = blockIdx.x;
    const int t = threadIdx.x;
    const float a = tex[b * 512 + t];
    const float c = tex[b * 512 + 256 + t];
    red[t] = a * a + c * c;
    __syncthreads();
    for (int s = 128; s > 0; s >>= 1) {
        if (t < s) red[t] += red[t + s];
        __syncthreads();
    }
    const float inv = 1.f / (sqrtf(red[0]) + 1e-8f);
    out[b * 512 + t] = a * inv;
    out[b * 512 + 256 + t] = c * inv;
}

extern "C" void kernel_launch(void* const* d_in, const int* in_sizes, int n_in,
                              void* d_out, int out_size, void* d_ws, size_t ws_size,
                              hipStream_t stream)
{
    const float* cap = (const float*)d_in[0];
    const int* lengths = (const int*)d_in[1];
    const float* Wq  = (const float*)d_in[2];
    const float* Wk  = (const float*)d_in[3];
    const float* Wv  = (const float*)d_in[4];
    const float* bq  = (const float*)d_in[5];
    const float* bk  = (const float*)d_in[6];
    const float* bv  = (const float*)d_in[7];
    const float* Wfq = (const float*)d_in[8];
    const float* bfq = (const float*)d_in[9];
    const float* Wfk = (const float*)d_in[10];
    const float* bfk = (const float*)d_in[11];
    const float* Wfg = (const float*)d_in[12];
    const float* bfg = (const float*)d_in[13];
    const float* g1  = (const float*)d_in[14];
    const float* b1  = (const float*)d_in[15];
    const float* m1  = (const float*)d_in[16];
    const float* v1  = (const float*)d_in[17];
    const float* Wm1 = (const float*)d_in[30];
    const float* bm1 = (const float*)d_in[31];
    const float* Wm2 = (const float*)d_in[32];
    const float* bm2 = (const float*)d_in[33];
    float* out = (float*)d_out;

    char* w = (char*)d_ws;
    const size_t MB = 1024 * 1024;
    short* capHi = (short*)(w);                // 32MB (stays valid; pbar reads it)
    short* capLo = (short*)(w + 32 * MB);      // 32MB
    short* KAhi  = (short*)(w + 64 * MB);      // 64MB  [32768,1024]: 0-511 K, 512-1023 A
    short* KAlo  = (short*)(w + 128 * MB);     // 64MB  (only K-half written/used)
    short* Gbuf  = (short*)(w + 192 * MB);     // 32MB  [32768,512] bf16
    char* wp = w + 224 * MB;
    short* WkHi  = (short*)wp; wp += 524288;   // [512,512]
    short* WkLo  = (short*)wp; wp += 524288;
    short* WaHi  = (short*)wp; wp += 524288;   // [512,512] composed
    short* WfkHi = (short*)wp; wp += 131072;
    short* WfkLo = (short*)wp; wp += 131072;   // written, unused
    short* Wfg2Hi = (short*)wp; wp += 131072;
    short* Wfg2Lo = (short*)wp; wp += 131072;  // written, unused
    float* ba     = (float*)wp; wp += 2048;
    float* qg     = (float*)wp; wp += 262144;
    float* scorep = (float*)wp; wp += 524288;   // [128][2][256][2]
    float* pbar   = (float*)wp; wp += 524288;
    float* xga    = (float*)wp; wp += 262144;
    float* hid    = (float*)wp; wp += 524288;
    float* tex    = (float*)wp; wp += 262144;

    // 1. splits: cap, Wk, Wfk, Wfg2
    SplitArgs sa;
    sa.src[0] = cap;          sa.hi[0] = capHi;  sa.lo[0] = capLo;  sa.n4[0] = 4194304;
    sa.src[1] = Wk;           sa.hi[1] = WkHi;   sa.lo[1] = WkLo;   sa.n4[1] = 65536;
    sa.src[2] = Wfk;          sa.hi[2] = WfkHi;  sa.lo[2] = WfkLo;  sa.n4[2] = 16384;
    sa.src[3] = Wfg + 65536;  sa.hi[3] = Wfg2Hi; sa.lo[3] = Wfg2Lo; sa.n4[3] = 16384;
    split_multi<<<dim3(4096, 4), 256, 0, stream>>>(sa);

    // 2. composed Wa (bf16), ba
    compose<<<dim3(512), 256, 0, stream>>>(Wq, bq, Wfq, bfq, WaHi, ba);

    // 3. K projection: 3-pass split -> KA cols 0-511
    gemm2p<3, 1><<<dim3(4, 256, 1), 256, 0, stream>>>(
        capHi, capLo, 512, 0, WkHi, WkLo, 512, bk,
        nullptr, nullptr, 0, 0, nullptr, nullptr,
        KAhi, KAlo, 1024, 0, 512);

    // 4. A = Fq(Q): 1-pass bf16 -> KA cols 512-1023
    gemm2p<1, 2><<<dim3(4, 256, 1), 256, 0, stream>>>(
        capHi, nullptr, 512, 0, WaHi, nullptr, 512, ba,
        nullptr, nullptr, 0, 0, nullptr, nullptr,
        KAhi + 512, nullptr, 1024, 0, 512);

    // 5. G = (K_h Wfk^T + bfk) * A : 1-pass bf16 -> Gbuf
    gemm2p<1, 3><<<dim3(2, 256, 2), 256, 0, stream>>>(
        KAhi, nullptr, 1024, 256, WfkHi, nullptr, 256, bfk,
        KAhi + 512, nullptr, 1024, 256, nullptr, nullptr,
        Gbuf, nullptr, 512, 256, 256);

    // 6. qg at gathered rows (Q fp32 from cap)
    qg_kernel<<<dim3(256), 256, 0, stream>>>(cap, Gbuf, Wq, bq, Wfg, bfg, lengths, qg);

    // 7. kg gemm + fused score partials (1-pass gemm; K read split)
    gemm2p<1, 4><<<dim3(2, 256, 2), 256, 0, stream>>>(
        Gbuf, nullptr, 512, 256, Wfg2Hi, nullptr, 256, bfg + 256,
        KAhi, KAlo, 1024, 256, qg, scorep,
        nullptr, nullptr, 0, 0, 256);

    // 8-9. softmax+pbar (bf16 cap), BN/residual
    pbar_kernel<<<dim3(8, 128), 256, 0, stream>>>(scorep, capHi, pbar);
    bnx_kernel<<<dim3(128), 256, 0, stream>>>(pbar, cap, lengths, Wv, bv, g1, b1, m1, v1, xga);

    // 10-12. MLP, norm
    mlp1<<<dim3(16, 8), 256, 0, stream>>>(xga, Wm1, bm1, hid);
    mlp2<<<dim3(8, 8), 256, 0, stream>>>(hid, Wm2, bm2, xga, tex);
    norm_out<<<dim3(128), 256, 0, stream>>>(tex, out);
}

// Round 13
// 307.802 us; speedup vs baseline: 1.1591x; 1.0855x over previous
//
#include <hip/hip_runtime.h>
#include <math.h>

// BS=128, L=256, D=512, H=2, DK=256.
// Conv branches dead (gather idx < 256). Split-bf16 MFMA GEMMs, all 2-phase
// __syncthreads-only (no manual barriers/vmcnt). A = Fq(Q(x)) via composed
// weight, fused into G's dual K-loop (never materialized); V GEMM removed via
// x=(p@cap)@Wv^T+bv. Gate-shielding: G, kg-gemm 1-pass bf16; K 3-pass split.

typedef short bf16x8 __attribute__((ext_vector_type(8)));
typedef float f32x4 __attribute__((ext_vector_type(4)));
typedef short short4v __attribute__((ext_vector_type(4)));

__device__ __forceinline__ short f2bf(float x) {
    union { float f; unsigned u; } c; c.f = x;
    unsigned r = c.u + 0x7FFFu + ((c.u >> 16) & 1u);
    return (short)(r >> 16);
}
__device__ __forceinline__ float bf2f(short h) {
    union { float f; unsigned u; } c; c.u = ((unsigned)(unsigned short)h) << 16;
    return c.f;
}
__device__ __forceinline__ void glds16(const void* g, void* l) {
    __builtin_amdgcn_global_load_lds(
        (const __attribute__((address_space(1))) void*)g,
        (__attribute__((address_space(3))) void*)l, 16, 0, 0);
}

// ---------------- split fp32 -> bf16 hi/lo ----------------
struct SplitArgs {
    const float* src[4];
    short* hi[4];
    short* lo[4];
    int n4[4];
};
__global__ __launch_bounds__(256) void split_multi(SplitArgs a)
{
    const int j = blockIdx.y;
    const float4* s = (const float4*)a.src[j];
    short* hi = a.hi[j];
    short* lo = a.lo[j];
    const int n4 = a.n4[j];
    for (int i = blockIdx.x * 256 + threadIdx.x; i < n4; i += gridDim.x * 256) {
        float4 x = s[i];
        short4v h, l;
        h.x = f2bf(x.x); l.x = f2bf(x.x - bf2f(h.x));
        h.y = f2bf(x.y); l.y = f2bf(x.y - bf2f(h.y));
        h.z = f2bf(x.z); l.z = f2bf(x.z - bf2f(h.z));
        h.w = f2bf(x.w); l.w = f2bf(x.w - bf2f(h.w));
        *(short4v*)&hi[i * 4] = h;
        *(short4v*)&lo[i * 4] = l;
    }
}

// ---------------- composed weight Wa = Wfq @ Wq_h (bf16), ba = Wfq@bq_h + bfq ----
__global__ __launch_bounds__(256)
void compose(const float* __restrict__ Wq, const float* __restrict__ bq,
             const float* __restrict__ Wfq, const float* __restrict__ bfq,
             short* __restrict__ WaHi, float* __restrict__ ba)
{
    __shared__ float fq[256];
    __shared__ float redc[256];
    const int op = blockIdx.x;          // 0..511: h = op>>8, o = op&255
    const int h = op >> 8, o = op & 255;
    const int t = threadIdx.x;
    fq[t] = Wfq[o * 256 + t];
    redc[t] = fq[t] * bq[h * 256 + t];
    __syncthreads();
    for (int s = 128; s > 0; s >>= 1) {
        if (t < s) redc[t] += redc[t + s];
        __syncthreads();
    }
    if (t == 0) ba[op] = redc[0] + bfq[o];
    float s0 = 0.f, s1 = 0.f;
    for (int d = 0; d < 256; ++d) {
        const float f = fq[d];
        const float* wr = Wq + (size_t)(h * 256 + d) * 512;
        s0 += f * wr[t];
        s1 += f * wr[t + 256];
    }
    const size_t ro = (size_t)op * 512;
    WaHi[ro + t] = f2bf(s0);
    WaHi[ro + 256 + t] = f2bf(s1);
}

// ---------------- shared 1-pass K-loop (2-phase, __syncthreads-only) ----------------
__device__ __forceinline__ void kloop_1p(
    const short* __restrict__ A, int lda,
    const short* __restrict__ B, int ldb,
    int K, int bm, int bn, short (*lds)[8192], int tid, f32x4 acc[4][4])
{
    const int lane = tid & 63;
    const int wr = (tid >> 7) & 1, wc = (tid >> 6) & 1;
    const int fr = lane & 15, kc = lane >> 4;
    const int r0 = tid >> 2;
    const int e0 = (((tid & 3) ^ ((r0 >> 1) & 3))) * 8;
    const int kce = (kc ^ ((fr >> 1) & 3)) * 8;

    auto stage = [&](int ph, int k0) {
        short* b = lds[ph];
        glds16(A + (size_t)(bm + r0) * lda + k0 + e0,      b + tid * 8);
        glds16(A + (size_t)(bm + r0 + 64) * lda + k0 + e0, b + (tid + 256) * 8);
        glds16(B + (size_t)(bn + r0) * ldb + k0 + e0,      b + 4096 + tid * 8);
        glds16(B + (size_t)(bn + r0 + 64) * ldb + k0 + e0, b + 4096 + (tid + 256) * 8);
    };

    stage(0, 0);
    __syncthreads();
    const int NS = K / 32;
    for (int s = 0; s < NS; ++s) {
        if (s + 1 < NS) stage((s + 1) & 1, (s + 1) * 32);
        const short* b = lds[s & 1];
        bf16x8 ah[4], bh[4];
#pragma unroll
        for (int i = 0; i < 4; ++i)
            ah[i] = *(const bf16x8*)&b[(wr * 64 + i * 16 + fr) * 32 + kce];
#pragma unroll
        for (int i = 0; i < 4; ++i)
            bh[i] = *(const bf16x8*)&b[4096 + (wc * 64 + i * 16 + fr) * 32 + kce];
#pragma unroll
        for (int mi = 0; mi < 4; ++mi)
#pragma unroll
            for (int ni = 0; ni < 4; ++ni)
                acc[mi][ni] = __builtin_amdgcn_mfma_f32_16x16x32_bf16(ah[mi], bh[ni], acc[mi][ni], 0, 0, 0);
        __syncthreads();
    }
}

// ---------------- K projection: 3-pass split, split write ----------------
__global__ __launch_bounds__(256, 2)
void gemm_k(const short* __restrict__ capHi, const short* __restrict__ capLo,
            const short* __restrict__ WkHi, const short* __restrict__ WkLo,
            const float* __restrict__ bk,
            short* __restrict__ KAhi, short* __restrict__ KAlo)
{
    __shared__ short lds[2][16384];
    const int tid = threadIdx.x;
    const int bm = blockIdx.y * 128;
    const int bn = blockIdx.x * 128;

    const int lane = tid & 63;
    const int wr = (tid >> 7) & 1, wc = (tid >> 6) & 1;
    const int fr = lane & 15, kc = lane >> 4;
    const int r0 = tid >> 2;
    const int e0 = (((tid & 3) ^ ((r0 >> 1) & 3))) * 8;
    const int kce = (kc ^ ((fr >> 1) & 3)) * 8;

    auto stage = [&](int ph, int k0) {
        short* b = lds[ph];
        glds16(capHi + (size_t)(bm + r0) * 512 + k0 + e0,       b + tid * 8);
        glds16(capHi + (size_t)(bm + r0 + 64) * 512 + k0 + e0,  b + (tid + 256) * 8);
        glds16(WkHi + (size_t)(bn + r0) * 512 + k0 + e0,        b + 4096 + tid * 8);
        glds16(WkHi + (size_t)(bn + r0 + 64) * 512 + k0 + e0,   b + 4096 + (tid + 256) * 8);
        glds16(capLo + (size_t)(bm + r0) * 512 + k0 + e0,       b + 8192 + tid * 8);
        glds16(capLo + (size_t)(bm + r0 + 64) * 512 + k0 + e0,  b + 8192 + (tid + 256) * 8);
        glds16(WkLo + (size_t)(bn + r0) * 512 + k0 + e0,        b + 12288 + tid * 8);
        glds16(WkLo + (size_t)(bn + r0 + 64) * 512 + k0 + e0,   b + 12288 + (tid + 256) * 8);
    };

    f32x4 acc[4][4];
#pragma unroll
    for (int i = 0; i < 4; ++i)
#pragma unroll
        for (int j = 0; j < 4; ++j) acc[i][j] = (f32x4){0.f, 0.f, 0.f, 0.f};

    stage(0, 0);
    __syncthreads();
    for (int s = 0; s < 16; ++s) {
        if (s + 1 < 16) stage((s + 1) & 1, (s + 1) * 32);
        const short* b = lds[s & 1];
        bf16x8 ah[4], bh[4], al[4], bl[4];
#pragma unroll
        for (int i = 0; i < 4; ++i)
            ah[i] = *(const bf16x8*)&b[(wr * 64 + i * 16 + fr) * 32 + kce];
#pragma unroll
        for (int i = 0; i < 4; ++i)
            bh[i] = *(const bf16x8*)&b[4096 + (wc * 64 + i * 16 + fr) * 32 + kce];
#pragma unroll
        for (int mi = 0; mi < 4; ++mi)
#pragma unroll
            for (int ni = 0; ni < 4; ++ni)
                acc[mi][ni] = __builtin_amdgcn_mfma_f32_16x16x32_bf16(ah[mi], bh[ni], acc[mi][ni], 0, 0, 0);
#pragma unroll
        for (int i = 0; i < 4; ++i)
            al[i] = *(const bf16x8*)&b[8192 + (wr * 64 + i * 16 + fr) * 32 + kce];
#pragma unroll
        for (int mi = 0; mi < 4; ++mi)
#pragma unroll
            for (int ni = 0; ni < 4; ++ni)
                acc[mi][ni] = __builtin_amdgcn_mfma_f32_16x16x32_bf16(al[mi], bh[ni], acc[mi][ni], 0, 0, 0);
#pragma unroll
        for (int i = 0; i < 4; ++i)
            bl[i] = *(const bf16x8*)&b[12288 + (wc * 64 + i * 16 + fr) * 32 + kce];
#pragma unroll
        for (int mi = 0; mi < 4; ++mi)
#pragma unroll
            for (int ni = 0; ni < 4; ++ni)
                acc[mi][ni] = __builtin_amdgcn_mfma_f32_16x16x32_bf16(ah[mi], bl[ni], acc[mi][ni], 0, 0, 0);
        __syncthreads();
    }

#pragma unroll
    for (int mi = 0; mi < 4; ++mi) {
#pragma unroll
        for (int ni = 0; ni < 4; ++ni) {
#pragma unroll
            for (int r = 0; r < 4; ++r) {
                const int row = bm + wr * 64 + mi * 16 + kc * 4 + r;
                const int col = bn + wc * 64 + ni * 16 + fr;
                const float v = acc[mi][ni][r] + bk[col];
                const size_t off = (size_t)row * 1024 + col;
                short h = f2bf(v);
                KAhi[off] = h;
                KAlo[off] = f2bf(v - bf2f(h));
            }
        }
    }
}

// ---------------- fused G: dual K-loop, G = (K@Wfk^T+bfk)*(cap@Wa^T+ba) ----------------
__global__ __launch_bounds__(256, 2)
void gemm_g(const short* __restrict__ KAhi,
            const short* __restrict__ capHi,
            const short* __restrict__ WfkHi, const short* __restrict__ WaHi,
            const float* __restrict__ bfk, const float* __restrict__ ba,
            short* __restrict__ Gbuf)
{
    __shared__ short lds[2][8192];
    const int tid = threadIdx.x;
    const int bm = blockIdx.y * 128;
    const int bn = blockIdx.x * 128;   // 0 or 128 (within-head col)
    const int z = blockIdx.z;

    f32x4 acc1[4][4], acc2[4][4];
#pragma unroll
    for (int i = 0; i < 4; ++i)
#pragma unroll
        for (int j = 0; j < 4; ++j) {
            acc1[i][j] = (f32x4){0.f, 0.f, 0.f, 0.f};
            acc2[i][j] = (f32x4){0.f, 0.f, 0.f, 0.f};
        }

    // acc1 = K_h @ Wfk^T   (K from KA cols z*256.., K-dim 256)
    kloop_1p(KAhi + (size_t)z * 256, 1024, WfkHi, 256, 256, bm, bn, lds, tid, acc1);
    // acc2 = cap @ Wa_h^T  (K-dim 512)
    kloop_1p(capHi, 512, WaHi + (size_t)z * 256 * 512, 512, 512, bm, bn, lds, tid, acc2);

    const int lane = tid & 63;
    const int wr = (tid >> 7) & 1, wc = (tid >> 6) & 1;
    const int fr = lane & 15, kc = lane >> 4;
#pragma unroll
    for (int mi = 0; mi < 4; ++mi) {
#pragma unroll
        for (int ni = 0; ni < 4; ++ni) {
#pragma unroll
            for (int r = 0; r < 4; ++r) {
                const int row = bm + wr * 64 + mi * 16 + kc * 4 + r;
                const int col = bn + wc * 64 + ni * 16 + fr;
                const float lin = acc1[mi][ni][r] + bfk[col];
                const float av  = acc2[mi][ni][r] + ba[z * 256 + col];
                Gbuf[(size_t)row * 512 + z * 256 + col] = f2bf(lin * av);
            }
        }
    }
}

// ---------------- kg GEMM + fused score partials (1-pass; K read split) ----------------
__global__ __launch_bounds__(256, 2)
void gemm_kg(const short* __restrict__ Gbuf,
             const short* __restrict__ Wfg2Hi, const float* __restrict__ bias,
             const short* __restrict__ KAhi, const short* __restrict__ KAlo,
             const float* __restrict__ qg, float* __restrict__ scorep)
{
    __shared__ short lds[2][8192];
    __shared__ float sp[256];
    const int tid = threadIdx.x;
    const int bm = blockIdx.y * 128;
    const int bn = blockIdx.x * 128;
    const int z = blockIdx.z;

    f32x4 acc[4][4];
#pragma unroll
    for (int i = 0; i < 4; ++i)
#pragma unroll
        for (int j = 0; j < 4; ++j) acc[i][j] = (f32x4){0.f, 0.f, 0.f, 0.f};

    kloop_1p(Gbuf + (size_t)z * 256, 512, Wfg2Hi, 256, 256, bm, bn, lds, tid, acc);

    const int lane = tid & 63;
    const int wr = (tid >> 7) & 1, wc = (tid >> 6) & 1;
    const int fr = lane & 15, kc = lane >> 4;

    float qgv[4];
    float pt[4][4];
    {
        const int b = bm >> 8;
#pragma unroll
        for (int ni = 0; ni < 4; ++ni)
            qgv[ni] = qg[b * 512 + z * 256 + bn + wc * 64 + ni * 16 + fr];
#pragma unroll
        for (int mi = 0; mi < 4; ++mi)
#pragma unroll
            for (int r = 0; r < 4; ++r) pt[mi][r] = 0.f;
    }

#pragma unroll
    for (int mi = 0; mi < 4; ++mi) {
#pragma unroll
        for (int ni = 0; ni < 4; ++ni) {
#pragma unroll
            for (int r = 0; r < 4; ++r) {
                const int row = bm + wr * 64 + mi * 16 + kc * 4 + r;
                const int col = bn + wc * 64 + ni * 16 + fr;
                const float v = acc[mi][ni][r] + bias[col];
                const size_t eoffs = (size_t)row * 1024 + (size_t)z * 256 + col;
                const float e = bf2f(KAhi[eoffs]) + bf2f(KAlo[eoffs]);
                const float kgv = e / (1.f + expf(-v));
                pt[mi][r] += kgv * qgv[ni];
            }
        }
    }

#pragma unroll
    for (int mi = 0; mi < 4; ++mi) {
#pragma unroll
        for (int r = 0; r < 4; ++r) {
            float p = pt[mi][r];
            p += __shfl_xor(p, 1);
            p += __shfl_xor(p, 2);
            p += __shfl_xor(p, 4);
            p += __shfl_xor(p, 8);
            if (fr == 0) {
                const int row_local = wr * 64 + mi * 16 + kc * 4 + r;
                sp[row_local * 2 + wc] = p;
            }
        }
    }
    __syncthreads();
    if (tid < 128) {
        const int row = bm + tid;
        const float s = sp[tid * 2] + sp[tid * 2 + 1];
        const int b = row >> 8, j = row & 255;
        scorep[((size_t)(b * 2 + z) * 256 + j) * 2 + blockIdx.x] = s;
    }
}

// ---------------- qg at gathered rows: Q fp32-exact from cap ----------------
__global__ __launch_bounds__(256)
void qg_kernel(const float* __restrict__ cap,
               const short* __restrict__ Gbuf,
               const float* __restrict__ Wq, const float* __restrict__ bq,
               const float* __restrict__ Wfg, const float* __restrict__ bfg,
               const int* __restrict__ lengths, float* __restrict__ qg)
{
    __shared__ float cr[512];
    __shared__ float gs[256];
    const int b = blockIdx.x >> 1, h = blockIdx.x & 1;
    const int t = threadIdx.x;
    int r = lengths[b] - 1;
    if (r < 0) r = 0;
    if (r > 255) r = 255;
    const size_t base = ((size_t)b * 256 + r) * 512;
    cr[t] = cap[base + t];
    cr[t + 256] = cap[base + 256 + t];
    gs[t] = bf2f(Gbuf[base + h * 256 + t]);
    __syncthreads();
    const float4* wq4 = (const float4*)(Wq + (size_t)(h * 256 + t) * 512);
    float q = 0.f;
    for (int k4 = 0; k4 < 128; ++k4) {
        float4 w = wq4[k4];
        q += w.x * cr[k4 * 4 + 0] + w.y * cr[k4 * 4 + 1]
           + w.z * cr[k4 * 4 + 2] + w.w * cr[k4 * 4 + 3];
    }
    q += bq[h * 256 + t];
    const float4* w4 = (const float4*)(Wfg + (size_t)t * 256);
    float a = 0.f;
    for (int k4 = 0; k4 < 64; ++k4) {
        float4 w = w4[k4];
        a += w.x * gs[k4 * 4 + 0] + w.y * gs[k4 * 4 + 1]
           + w.z * gs[k4 * 4 + 2] + w.w * gs[k4 * 4 + 3];
    }
    a += bfg[t];
    qg[b * 512 + h * 256 + t] = q / (1.f + expf(-a));
}

// ---------------- softmax (inline) + pbar from bf16 capHi ----------------
__global__ __launch_bounds__(256)
void pbar_kernel(const float* __restrict__ scorep, const short* __restrict__ capHi,
                 float* __restrict__ pbar)
{
    __shared__ float sc[512], red[512];
    const int b = blockIdx.y, cg = blockIdx.x;
    const int t = threadIdx.x;
#pragma unroll
    for (int i = 0; i < 2; ++i) {
        const int o = t + i * 256;
        const int h = o >> 8, j = o & 255;
        const size_t si = ((size_t)(b * 2 + h) * 256 + j) * 2;
        sc[o] = floorf((scorep[si] + scorep[si + 1]) * 0.0625f);
    }
    __syncthreads();
    red[t] = sc[t]; red[t + 256] = sc[t + 256];
    __syncthreads();
    for (int s = 128; s > 0; s >>= 1) {
        if (t < s) {
            red[t] = fmaxf(red[t], red[t + s]);
            red[256 + t] = fmaxf(red[256 + t], red[256 + t + s]);
        }
        __syncthreads();
    }
    const float mx0 = red[0], mx1 = red[256];
    __syncthreads();
    const float e0 = expf(sc[t] - mx0);
    const float e1 = expf(sc[t + 256] - mx1);
    red[t] = e0; red[t + 256] = e1;
    __syncthreads();
    for (int s = 128; s > 0; s >>= 1) {
        if (t < s) { red[t] += red[t + s]; red[256 + t] += red[256 + t + s]; }
        __syncthreads();
    }
    sc[t] = e0 / red[0];
    sc[t + 256] = e1 / red[256];
    __syncthreads();

    const int c = cg * 64 + (t & 63);
    const int jg = t >> 6;
    float a0 = 0.f, a1 = 0.f;
    for (int j = jg * 64; j < jg * 64 + 64; ++j) {
        const float cv = bf2f(capHi[((size_t)(b * 256 + j)) * 512 + c]);
        a0 += sc[j] * cv;
        a1 += sc[256 + j] * cv;
    }
    red[t] = a0;
    __syncthreads();
    if (t < 64) {
        const float s0 = red[t] + red[t + 64] + red[t + 128] + red[t + 192];
        pbar[b * 1024 + cg * 64 + t] = s0;
    }
    __syncthreads();
    red[t] = a1;
    __syncthreads();
    if (t < 64) {
        const float s1 = red[t] + red[t + 64] + red[t + 128] + red[t + 192];
        pbar[b * 1024 + 512 + cg * 64 + t] = s1;
    }
}

// ---------------- x = pbar@Wv^T + bv, BN1, residual ----------------
__global__ __launch_bounds__(256)
void bnx_kernel(const float* __restrict__ pbar, const float* __restrict__ cap,
                const int* __restrict__ lengths,
                const float* __restrict__ Wv, const float* __restrict__ bv,
                const float* __restrict__ g1, const float* __restrict__ b1,
                const float* __restrict__ m1, const float* __restrict__ v1,
                float* __restrict__ xga)
{
    __shared__ float pb[1024];
    const int b = blockIdx.x;
    const int t = threadIdx.x;
    int r = lengths[b] - 1;
    if (r < 0) r = 0;
    if (r > 255) r = 255;
    const size_t base = ((size_t)b * 256 + r) * 512;
    pb[t] = pbar[b * 1024 + t];
    pb[t + 256] = pbar[b * 1024 + 256 + t];
    pb[t + 512] = pbar[b * 1024 + 512 + t];
    pb[t + 768] = pbar[b * 1024 + 768 + t];
    __syncthreads();
    float x0 = 0.f, x1 = 0.f;
    {
        const float4* w4 = (const float4*)(Wv + (size_t)t * 512);
        for (int k4 = 0; k4 < 128; ++k4) {
            float4 w = w4[k4];
            x0 += w.x * pb[k4 * 4 + 0] + w.y * pb[k4 * 4 + 1]
                + w.z * pb[k4 * 4 + 2] + w.w * pb[k4 * 4 + 3];
        }
        x0 += bv[t];
    }
    {
        const float4* w4 = (const float4*)(Wv + (size_t)(t + 256) * 512);
        for (int k4 = 0; k4 < 128; ++k4) {
            float4 w = w4[k4];
            x1 += w.x * pb[512 + k4 * 4 + 0] + w.y * pb[512 + k4 * 4 + 1]
                + w.z * pb[512 + k4 * 4 + 2] + w.w * pb[512 + k4 * 4 + 3];
        }
        x1 += bv[t + 256];
    }
    const int c0 = t, c1 = t + 256;
    const float s0 = g1[c0] / sqrtf(v1[c0] + 1e-5f);
    const float s1 = g1[c1] / sqrtf(v1[c1] + 1e-5f);
    xga[b * 512 + c0] = cap[base + c0] + (x0 - m1[c0]) * s0 + b1[c0];
    xga[b * 512 + c1] = cap[base + c1] + (x1 - m1[c1]) * s1 + b1[c1];
}

// ---------------- MLP strip GEMMs (weights read once) ----------------
__global__ __launch_bounds__(256)
void mlp1(const float* __restrict__ xga, const float* __restrict__ W,
          const float* __restrict__ bias, float* __restrict__ hid)
{
    __shared__ float xs[16 * 512];
    const int r0 = blockIdx.y * 16;
    const int c0 = blockIdx.x * 64;
    for (int i = threadIdx.x; i < 2048; i += 256)
        ((float4*)xs)[i] = ((const float4*)(xga + (size_t)r0 * 512))[i];
    __syncthreads();
    const int col = c0 + (threadIdx.x & 63);
    const int rg = (threadIdx.x >> 6) * 4;
    float acc[4] = {0.f, 0.f, 0.f, 0.f};
    const float4* w4 = (const float4*)(W + (size_t)col * 512);
    for (int k4 = 0; k4 < 128; ++k4) {
        float4 w = w4[k4];
#pragma unroll
        for (int rr = 0; rr < 4; ++rr) {
            float4 x = *(const float4*)&xs[(rg + rr) * 512 + k4 * 4];
            acc[rr] += w.x * x.x + w.y * x.y + w.z * x.z + w.w * x.w;
        }
    }
    const float bb = bias[col];
#pragma unroll
    for (int rr = 0; rr < 4; ++rr)
        hid[(size_t)(r0 + rg + rr) * 1024 + col] = fmaxf(acc[rr] + bb, 0.f);
}

__global__ __launch_bounds__(256)
void mlp2(const float* __restrict__ hid, const float* __restrict__ W,
          const float* __restrict__ bias, const float* __restrict__ xga,
          float* __restrict__ tex)
{
    __shared__ float xs[16 * 1024];
    const int r0 = blockIdx.y * 16;
    const int c0 = blockIdx.x * 64;
    for (int i = threadIdx.x; i < 4096; i += 256)
        ((float4*)xs)[i] = ((const float4*)(hid + (size_t)r0 * 1024))[i];
    __syncthreads();
    const int col = c0 + (threadIdx.x & 63);
    const int rg = (threadIdx.x >> 6) * 4;
    float acc[4] = {0.f, 0.f, 0.f, 0.f};
    const float4* w4 = (const float4*)(W + (size_t)col * 1024);
    for (int k4 = 0; k4 < 256; ++k4) {
        float4 w = w4[k4];
#pragma unroll
        for (int rr = 0; rr < 4; ++rr) {
            float4 x = *(const float4*)&xs[(rg + rr) * 1024 + k4 * 4];
            acc[rr] += w.x * x.x + w.y * x.y + w.z * x.z + w.w * x.w;
        }
    }
    const float bb = bias[col];
#pragma unroll
    for (int rr = 0; rr < 4; ++rr) {
        const int row = r0 + rg + rr;
        tex[(size_t)row * 512 + col] = acc[rr] + bb + xga[(size_t)row * 512 + col];
    }
}

__global__ __launch_bounds__(256)
void norm_out(const float* __restrict__ tex, float* __restrict__ out)
{
    __shared__ float red[256];
    const int b = blockIdx.x;
    const int t = threadIdx.x;
    const float a = tex[b * 512 + t];
    const float c = tex[b * 512 + 256 + t];
    red[t] = a * a + c * c;
    __syncthreads();
    for (int s = 128; s > 0; s >>= 1) {
        if (t < s) red[t] += red[t + s];
        __syncthreads();
    }
    const float inv = 1.f / (sqrtf(red[0]) + 1e-8f);
    out[b * 512 + t] = a * inv;
    out[b * 512 + 256 + t] = c * inv;
}

extern "C" void kernel_launch(void* const* d_in, const int* in_sizes, int n_in,
                              void* d_out, int out_size, void* d_ws, size_t ws_size,
                              hipStream_t stream)
{
    const float* cap = (const float*)d_in[0];
    const int* lengths = (const int*)d_in[1];
    const float* Wq  = (const float*)d_in[2];
    const float* Wk  = (const float*)d_in[3];
    const float* Wv  = (const float*)d_in[4];
    const float* bq  = (const float*)d_in[5];
    const float* bk  = (const float*)d_in[6];
    const float* bv  = (const float*)d_in[7];
    const float* Wfq = (const float*)d_in[8];
    const float* bfq = (const float*)d_in[9];
    const float* Wfk = (const float*)d_in[10];
    const float* bfk = (const float*)d_in[11];
    const float* Wfg = (const float*)d_in[12];
    const float* bfg = (const float*)d_in[13];
    const float* g1  = (const float*)d_in[14];
    const float* b1  = (const float*)d_in[15];
    const float* m1  = (const float*)d_in[16];
    const float* v1  = (const float*)d_in[17];
    const float* Wm1 = (const float*)d_in[30];
    const float* bm1 = (const float*)d_in[31];
    const float* Wm2 = (const float*)d_in[32];
    const float* bm2 = (const float*)d_in[33];
    float* out = (float*)d_out;

    char* w = (char*)d_ws;
    const size_t MB = 1024 * 1024;
    short* capHi = (short*)(w);                // 32MB (stays valid throughout)
    short* capLo = (short*)(w + 32 * MB);      // 32MB
    short* KAhi  = (short*)(w + 64 * MB);      // 64MB  [32768,1024]: cols 0-511 K (split)
    short* KAlo  = (short*)(w + 128 * MB);     // 64MB
    short* Gbuf  = (short*)(w + 192 * MB);     // 32MB  [32768,512] bf16
    char* wp = w + 224 * MB;
    short* WkHi  = (short*)wp; wp += 524288;   // [512,512]
    short* WkLo  = (short*)wp; wp += 524288;
    short* WaHi  = (short*)wp; wp += 524288;   // [512,512] composed (rows h*256+o)
    short* WfkHi = (short*)wp; wp += 131072;
    short* WfkLo = (short*)wp; wp += 131072;   // written, unused
    short* Wfg2Hi = (short*)wp; wp += 131072;
    short* Wfg2Lo = (short*)wp; wp += 131072;  // written, unused
    float* ba     = (float*)wp; wp += 2048;
    float* qg     = (float*)wp; wp += 262144;
    float* scorep = (float*)wp; wp += 524288;   // [128][2][256][2]
    float* pbar   = (float*)wp; wp += 524288;
    float* xga    = (float*)wp; wp += 262144;
    float* hid    = (float*)wp; wp += 524288;
    float* tex    = (float*)wp; wp += 262144;

    // 1. splits: cap, Wk, Wfk, Wfg2
    SplitArgs sa;
    sa.src[0] = cap;          sa.hi[0] = capHi;  sa.lo[0] = capLo;  sa.n4[0] = 4194304;
    sa.src[1] = Wk;           sa.hi[1] = WkHi;   sa.lo[1] = WkLo;   sa.n4[1] = 65536;
    sa.src[2] = Wfk;          sa.hi[2] = WfkHi;  sa.lo[2] = WfkLo;  sa.n4[2] = 16384;
    sa.src[3] = Wfg + 65536;  sa.hi[3] = Wfg2Hi; sa.lo[3] = Wfg2Lo; sa.n4[3] = 16384;
    split_multi<<<dim3(4096, 4), 256, 0, stream>>>(sa);

    // 2. composed Wa (bf16), ba
    compose<<<dim3(512), 256, 0, stream>>>(Wq, bq, Wfq, bfq, WaHi, ba);

    // 3. K projection: 3-pass split -> KA cols 0-511
    gemm_k<<<dim3(4, 256), 256, 0, stream>>>(capHi, capLo, WkHi, WkLo, bk, KAhi, KAlo);

    // 4. G = (K_h Wfk^T + bfk) * (cap Wa_h^T + ba)  (dual K-loop) -> Gbuf
    gemm_g<<<dim3(2, 256, 2), 256, 0, stream>>>(KAhi, capHi, WfkHi, WaHi, bfk, ba, Gbuf);

    // 5. qg at gathered rows (Q fp32 from cap)
    qg_kernel<<<dim3(256), 256, 0, stream>>>(cap, Gbuf, Wq, bq, Wfg, bfg, lengths, qg);

    // 6. kg gemm + fused score partials (1-pass gemm; K read split)
    gemm_kg<<<dim3(2, 256, 2), 256, 0, stream>>>(Gbuf, Wfg2Hi, bfg + 256,
                                                 KAhi, KAlo, qg, scorep);

    // 7-8. softmax+pbar (bf16 cap), BN/residual
    pbar_kernel<<<dim3(8, 128), 256, 0, stream>>>(scorep, capHi, pbar);
    bnx_kernel<<<dim3(128), 256, 0, stream>>>(pbar, cap, lengths, Wv, bv, g1, b1, m1, v1, xga);

    // 9-11. MLP, norm
    mlp1<<<dim3(16, 8), 256, 0, stream>>>(xga, Wm1, bm1, hid);
    mlp2<<<dim3(8, 8), 256, 0, stream>>>(hid, Wm2, bm2, xga, tex);
    norm_out<<<dim3(128), 256, 0, stream>>>(tex, out);
}

// Round 14
// 272.723 us; speedup vs baseline: 1.3082x; 1.1286x over previous
//
#include <hip/hip_runtime.h>
#include <math.h>

// BS=128, L=256, D=512, H=2, DK=256.
// Conv branches dead (gather idx < 256). ALL GEMMs 1-pass bf16 MFMA, 2-phase
// __syncthreads-only. Precision argument: floor(score/16) == sign(score)
// effectively (score sigma ~0.8 << 16); sign flips cost ~7e-5 on the
// l2-normalized output, so bf16 score-chain error (~3e-3) is safe under the
// 4e-3 threshold. A = Fq(Q(x)) fused into G's dual K-loop; V GEMM removed via
// x=(p@cap)@Wv^T+bv; kg never materialized (score fused into kg GEMM).

typedef short bf16x8 __attribute__((ext_vector_type(8)));
typedef float f32x4 __attribute__((ext_vector_type(4)));
typedef short short4v __attribute__((ext_vector_type(4)));

__device__ __forceinline__ short f2bf(float x) {
    union { float f; unsigned u; } c; c.f = x;
    unsigned r = c.u + 0x7FFFu + ((c.u >> 16) & 1u);
    return (short)(r >> 16);
}
__device__ __forceinline__ float bf2f(short h) {
    union { float f; unsigned u; } c; c.u = ((unsigned)(unsigned short)h) << 16;
    return c.f;
}
__device__ __forceinline__ void glds16(const void* g, void* l) {
    __builtin_amdgcn_global_load_lds(
        (const __attribute__((address_space(1))) void*)g,
        (__attribute__((address_space(3))) void*)l, 16, 0, 0);
}

// ---------------- cast fp32 -> bf16 ----------------
struct CastArgs {
    const float* src[4];
    short* dst[4];
    int n4[4];
};
__global__ __launch_bounds__(256) void cast_multi(CastArgs a)
{
    const int j = blockIdx.y;
    const float4* s = (const float4*)a.src[j];
    short* d = a.dst[j];
    const int n4 = a.n4[j];
    for (int i = blockIdx.x * 256 + threadIdx.x; i < n4; i += gridDim.x * 256) {
        float4 x = s[i];
        short4v h;
        h.x = f2bf(x.x); h.y = f2bf(x.y); h.z = f2bf(x.z); h.w = f2bf(x.w);
        *(short4v*)&d[i * 4] = h;
    }
}

// ---------------- composed weight Wa = Wfq @ Wq_h (bf16), ba = Wfq@bq_h + bfq ----
__global__ __launch_bounds__(256)
void compose(const float* __restrict__ Wq, const float* __restrict__ bq,
             const float* __restrict__ Wfq, const float* __restrict__ bfq,
             short* __restrict__ WaHi, float* __restrict__ ba)
{
    __shared__ float fq[256];
    __shared__ float redc[256];
    const int op = blockIdx.x;          // 0..511: h = op>>8, o = op&255
    const int h = op >> 8, o = op & 255;
    const int t = threadIdx.x;
    fq[t] = Wfq[o * 256 + t];
    redc[t] = fq[t] * bq[h * 256 + t];
    __syncthreads();
    for (int s = 128; s > 0; s >>= 1) {
        if (t < s) redc[t] += redc[t + s];
        __syncthreads();
    }
    if (t == 0) ba[op] = redc[0] + bfq[o];
    float s0 = 0.f, s1 = 0.f;
    for (int d = 0; d < 256; ++d) {
        const float f = fq[d];
        const float* wr = Wq + (size_t)(h * 256 + d) * 512;
        s0 += f * wr[t];
        s1 += f * wr[t + 256];
    }
    const size_t ro = (size_t)op * 512;
    WaHi[ro + t] = f2bf(s0);
    WaHi[ro + 256 + t] = f2bf(s1);
}

// ---------------- shared 1-pass K-loop (2-phase, __syncthreads-only) ----------------
__device__ __forceinline__ void kloop_1p(
    const short* __restrict__ A, int lda,
    const short* __restrict__ B, int ldb,
    int K, int bm, int bn, short (*lds)[8192], int tid, f32x4 acc[4][4])
{
    const int lane = tid & 63;
    const int wr = (tid >> 7) & 1, wc = (tid >> 6) & 1;
    const int fr = lane & 15, kc = lane >> 4;
    const int r0 = tid >> 2;
    const int e0 = (((tid & 3) ^ ((r0 >> 1) & 3))) * 8;
    const int kce = (kc ^ ((fr >> 1) & 3)) * 8;

    auto stage = [&](int ph, int k0) {
        short* b = lds[ph];
        glds16(A + (size_t)(bm + r0) * lda + k0 + e0,      b + tid * 8);
        glds16(A + (size_t)(bm + r0 + 64) * lda + k0 + e0, b + (tid + 256) * 8);
        glds16(B + (size_t)(bn + r0) * ldb + k0 + e0,      b + 4096 + tid * 8);
        glds16(B + (size_t)(bn + r0 + 64) * ldb + k0 + e0, b + 4096 + (tid + 256) * 8);
    };

    stage(0, 0);
    __syncthreads();
    const int NS = K / 32;
    for (int s = 0; s < NS; ++s) {
        if (s + 1 < NS) stage((s + 1) & 1, (s + 1) * 32);
        const short* b = lds[s & 1];
        bf16x8 ah[4], bh[4];
#pragma unroll
        for (int i = 0; i < 4; ++i)
            ah[i] = *(const bf16x8*)&b[(wr * 64 + i * 16 + fr) * 32 + kce];
#pragma unroll
        for (int i = 0; i < 4; ++i)
            bh[i] = *(const bf16x8*)&b[4096 + (wc * 64 + i * 16 + fr) * 32 + kce];
#pragma unroll
        for (int mi = 0; mi < 4; ++mi)
#pragma unroll
            for (int ni = 0; ni < 4; ++ni)
                acc[mi][ni] = __builtin_amdgcn_mfma_f32_16x16x32_bf16(ah[mi], bh[ni], acc[mi][ni], 0, 0, 0);
        __syncthreads();
    }
}

// ---------------- K projection: 1-pass bf16 ----------------
__global__ __launch_bounds__(256, 2)
void gemm_k1(const short* __restrict__ capB, const short* __restrict__ WkB,
             const float* __restrict__ bk, short* __restrict__ Kbuf)
{
    __shared__ short lds[2][8192];
    const int tid = threadIdx.x;
    const int bm = blockIdx.y * 128;
    const int bn = blockIdx.x * 128;

    f32x4 acc[4][4];
#pragma unroll
    for (int i = 0; i < 4; ++i)
#pragma unroll
        for (int j = 0; j < 4; ++j) acc[i][j] = (f32x4){0.f, 0.f, 0.f, 0.f};

    kloop_1p(capB, 512, WkB, 512, 512, bm, bn, lds, tid, acc);

    const int lane = tid & 63;
    const int wr = (tid >> 7) & 1, wc = (tid >> 6) & 1;
    const int fr = lane & 15, kc = lane >> 4;
#pragma unroll
    for (int mi = 0; mi < 4; ++mi) {
#pragma unroll
        for (int ni = 0; ni < 4; ++ni) {
#pragma unroll
            for (int r = 0; r < 4; ++r) {
                const int row = bm + wr * 64 + mi * 16 + kc * 4 + r;
                const int col = bn + wc * 64 + ni * 16 + fr;
                Kbuf[(size_t)row * 512 + col] = f2bf(acc[mi][ni][r] + bk[col]);
            }
        }
    }
}

// ---------------- fused G: dual K-loop, G = (K@Wfk^T+bfk)*(cap@Wa^T+ba) ----------------
__global__ __launch_bounds__(256, 2)
void gemm_g(const short* __restrict__ Kbuf,
            const short* __restrict__ capB,
            const short* __restrict__ WfkB, const short* __restrict__ WaB,
            const float* __restrict__ bfk, const float* __restrict__ ba,
            short* __restrict__ Gbuf)
{
    __shared__ short lds[2][8192];
    const int tid = threadIdx.x;
    const int bm = blockIdx.y * 128;
    const int bn = blockIdx.x * 128;   // 0 or 128 (within-head col)
    const int z = blockIdx.z;

    f32x4 acc1[4][4], acc2[4][4];
#pragma unroll
    for (int i = 0; i < 4; ++i)
#pragma unroll
        for (int j = 0; j < 4; ++j) {
            acc1[i][j] = (f32x4){0.f, 0.f, 0.f, 0.f};
            acc2[i][j] = (f32x4){0.f, 0.f, 0.f, 0.f};
        }

    // acc1 = K_h @ Wfk^T   (K_h = cols z*256.. of Kbuf, K-dim 256)
    kloop_1p(Kbuf + (size_t)z * 256, 512, WfkB, 256, 256, bm, bn, lds, tid, acc1);
    // acc2 = cap @ Wa_h^T  (K-dim 512)
    kloop_1p(capB, 512, WaB + (size_t)z * 256 * 512, 512, 512, bm, bn, lds, tid, acc2);

    const int lane = tid & 63;
    const int wr = (tid >> 7) & 1, wc = (tid >> 6) & 1;
    const int fr = lane & 15, kc = lane >> 4;
#pragma unroll
    for (int mi = 0; mi < 4; ++mi) {
#pragma unroll
        for (int ni = 0; ni < 4; ++ni) {
#pragma unroll
            for (int r = 0; r < 4; ++r) {
                const int row = bm + wr * 64 + mi * 16 + kc * 4 + r;
                const int col = bn + wc * 64 + ni * 16 + fr;
                const float lin = acc1[mi][ni][r] + bfk[col];
                const float av  = acc2[mi][ni][r] + ba[z * 256 + col];
                Gbuf[(size_t)row * 512 + z * 256 + col] = f2bf(lin * av);
            }
        }
    }
}

// ---------------- kg GEMM + fused score partials ----------------
__global__ __launch_bounds__(256, 2)
void gemm_kg(const short* __restrict__ Gbuf,
             const short* __restrict__ Wfg2B, const float* __restrict__ bias,
             const short* __restrict__ Kbuf,
             const float* __restrict__ qg, float* __restrict__ scorep)
{
    __shared__ short lds[2][8192];
    __shared__ float sp[256];
    const int tid = threadIdx.x;
    const int bm = blockIdx.y * 128;
    const int bn = blockIdx.x * 128;
    const int z = blockIdx.z;

    f32x4 acc[4][4];
#pragma unroll
    for (int i = 0; i < 4; ++i)
#pragma unroll
        for (int j = 0; j < 4; ++j) acc[i][j] = (f32x4){0.f, 0.f, 0.f, 0.f};

    kloop_1p(Gbuf + (size_t)z * 256, 512, Wfg2B, 256, 256, bm, bn, lds, tid, acc);

    const int lane = tid & 63;
    const int wr = (tid >> 7) & 1, wc = (tid >> 6) & 1;
    const int fr = lane & 15, kc = lane >> 4;

    float qgv[4];
    float pt[4][4];
    {
        const int b = bm >> 8;
#pragma unroll
        for (int ni = 0; ni < 4; ++ni)
            qgv[ni] = qg[b * 512 + z * 256 + bn + wc * 64 + ni * 16 + fr];
#pragma unroll
        for (int mi = 0; mi < 4; ++mi)
#pragma unroll
            for (int r = 0; r < 4; ++r) pt[mi][r] = 0.f;
    }

#pragma unroll
    for (int mi = 0; mi < 4; ++mi) {
#pragma unroll
        for (int ni = 0; ni < 4; ++ni) {
#pragma unroll
            for (int r = 0; r < 4; ++r) {
                const int row = bm + wr * 64 + mi * 16 + kc * 4 + r;
                const int col = bn + wc * 64 + ni * 16 + fr;
                const float v = acc[mi][ni][r] + bias[col];
                const float e = bf2f(Kbuf[(size_t)row * 512 + z * 256 + col]);
                const float kgv = e / (1.f + expf(-v));
                pt[mi][r] += kgv * qgv[ni];
            }
        }
    }

#pragma unroll
    for (int mi = 0; mi < 4; ++mi) {
#pragma unroll
        for (int r = 0; r < 4; ++r) {
            float p = pt[mi][r];
            p += __shfl_xor(p, 1);
            p += __shfl_xor(p, 2);
            p += __shfl_xor(p, 4);
            p += __shfl_xor(p, 8);
            if (fr == 0) {
                const int row_local = wr * 64 + mi * 16 + kc * 4 + r;
                sp[row_local * 2 + wc] = p;
            }
        }
    }
    __syncthreads();
    if (tid < 128) {
        const int row = bm + tid;
        const float s = sp[tid * 2] + sp[tid * 2 + 1];
        const int b = row >> 8, j = row & 255;
        scorep[((size_t)(b * 2 + z) * 256 + j) * 2 + blockIdx.x] = s;
    }
}

// ---------------- qg at gathered rows: Q fp32-exact from cap ----------------
__global__ __launch_bounds__(256)
void qg_kernel(const float* __restrict__ cap,
               const short* __restrict__ Gbuf,
               const float* __restrict__ Wq, const float* __restrict__ bq,
               const float* __restrict__ Wfg, const float* __restrict__ bfg,
               const int* __restrict__ lengths, float* __restrict__ qg)
{
    __shared__ float cr[512];
    __shared__ float gs[256];
    const int b = blockIdx.x >> 1, h = blockIdx.x & 1;
    const int t = threadIdx.x;
    int r = lengths[b] - 1;
    if (r < 0) r = 0;
    if (r > 255) r = 255;
    const size_t base = ((size_t)b * 256 + r) * 512;
    cr[t] = cap[base + t];
    cr[t + 256] = cap[base + 256 + t];
    gs[t] = bf2f(Gbuf[base + h * 256 + t]);
    __syncthreads();
    const float4* wq4 = (const float4*)(Wq + (size_t)(h * 256 + t) * 512);
    float q = 0.f;
    for (int k4 = 0; k4 < 128; ++k4) {
        float4 w = wq4[k4];
        q += w.x * cr[k4 * 4 + 0] + w.y * cr[k4 * 4 + 1]
           + w.z * cr[k4 * 4 + 2] + w.w * cr[k4 * 4 + 3];
    }
    q += bq[h * 256 + t];
    const float4* w4 = (const float4*)(Wfg + (size_t)t * 256);
    float a = 0.f;
    for (int k4 = 0; k4 < 64; ++k4) {
        float4 w = w4[k4];
        a += w.x * gs[k4 * 4 + 0] + w.y * gs[k4 * 4 + 1]
           + w.z * gs[k4 * 4 + 2] + w.w * gs[k4 * 4 + 3];
    }
    a += bfg[t];
    qg[b * 512 + h * 256 + t] = q / (1.f + expf(-a));
}

// ---------------- softmax (inline) + pbar from bf16 cap ----------------
__global__ __launch_bounds__(256)
void pbar_kernel(const float* __restrict__ scorep, const short* __restrict__ capB,
                 float* __restrict__ pbar)
{
    __shared__ float sc[512], red[512];
    const int b = blockIdx.y, cg = blockIdx.x;
    const int t = threadIdx.x;
#pragma unroll
    for (int i = 0; i < 2; ++i) {
        const int o = t + i * 256;
        const int h = o >> 8, j = o & 255;
        const size_t si = ((size_t)(b * 2 + h) * 256 + j) * 2;
        sc[o] = floorf((scorep[si] + scorep[si + 1]) * 0.0625f);
    }
    __syncthreads();
    red[t] = sc[t]; red[t + 256] = sc[t + 256];
    __syncthreads();
    for (int s = 128; s > 0; s >>= 1) {
        if (t < s) {
            red[t] = fmaxf(red[t], red[t + s]);
            red[256 + t] = fmaxf(red[256 + t], red[256 + t + s]);
        }
        __syncthreads();
    }
    const float mx0 = red[0], mx1 = red[256];
    __syncthreads();
    const float e0 = expf(sc[t] - mx0);
    const float e1 = expf(sc[t + 256] - mx1);
    red[t] = e0; red[t + 256] = e1;
    __syncthreads();
    for (int s = 128; s > 0; s >>= 1) {
        if (t < s) { red[t] += red[t + s]; red[256 + t] += red[256 + t + s]; }
        __syncthreads();
    }
    sc[t] = e0 / red[0];
    sc[t + 256] = e1 / red[256];
    __syncthreads();

    const int c = cg * 64 + (t & 63);
    const int jg = t >> 6;
    float a0 = 0.f, a1 = 0.f;
    for (int j = jg * 64; j < jg * 64 + 64; ++j) {
        const float cv = bf2f(capB[((size_t)(b * 256 + j)) * 512 + c]);
        a0 += sc[j] * cv;
        a1 += sc[256 + j] * cv;
    }
    red[t] = a0;
    __syncthreads();
    if (t < 64) {
        const float s0 = red[t] + red[t + 64] + red[t + 128] + red[t + 192];
        pbar[b * 1024 + cg * 64 + t] = s0;
    }
    __syncthreads();
    red[t] = a1;
    __syncthreads();
    if (t < 64) {
        const float s1 = red[t] + red[t + 64] + red[t + 128] + red[t + 192];
        pbar[b * 1024 + 512 + cg * 64 + t] = s1;
    }
}

// ---------------- x = pbar@Wv^T + bv, BN1, residual ----------------
__global__ __launch_bounds__(256)
void bnx_kernel(const float* __restrict__ pbar, const float* __restrict__ cap,
                const int* __restrict__ lengths,
                const float* __restrict__ Wv, const float* __restrict__ bv,
                const float* __restrict__ g1, const float* __restrict__ b1,
                const float* __restrict__ m1, const float* __restrict__ v1,
                float* __restrict__ xga)
{
    __shared__ float pb[1024];
    const int b = blockIdx.x;
    const int t = threadIdx.x;
    int r = lengths[b] - 1;
    if (r < 0) r = 0;
    if (r > 255) r = 255;
    const size_t base = ((size_t)b * 256 + r) * 512;
    pb[t] = pbar[b * 1024 + t];
    pb[t + 256] = pbar[b * 1024 + 256 + t];
    pb[t + 512] = pbar[b * 1024 + 512 + t];
    pb[t + 768] = pbar[b * 1024 + 768 + t];
    __syncthreads();
    float x0 = 0.f, x1 = 0.f;
    {
        const float4* w4 = (const float4*)(Wv + (size_t)t * 512);
        for (int k4 = 0; k4 < 128; ++k4) {
            float4 w = w4[k4];
            x0 += w.x * pb[k4 * 4 + 0] + w.y * pb[k4 * 4 + 1]
                + w.z * pb[k4 * 4 + 2] + w.w * pb[k4 * 4 + 3];
        }
        x0 += bv[t];
    }
    {
        const float4* w4 = (const float4*)(Wv + (size_t)(t + 256) * 512);
        for (int k4 = 0; k4 < 128; ++k4) {
            float4 w = w4[k4];
            x1 += w.x * pb[512 + k4 * 4 + 0] + w.y * pb[512 + k4 * 4 + 1]
                + w.z * pb[512 + k4 * 4 + 2] + w.w * pb[512 + k4 * 4 + 3];
        }
        x1 += bv[t + 256];
    }
    const int c0 = t, c1 = t + 256;
    const float s0 = g1[c0] / sqrtf(v1[c0] + 1e-5f);
    const float s1 = g1[c1] / sqrtf(v1[c1] + 1e-5f);
    xga[b * 512 + c0] = cap[base + c0] + (x0 - m1[c0]) * s0 + b1[c0];
    xga[b * 512 + c1] = cap[base + c1] + (x1 - m1[c1]) * s1 + b1[c1];
}

// ---------------- MLP strip GEMMs (weights read once) ----------------
__global__ __launch_bounds__(256)
void mlp1(const float* __restrict__ xga, const float* __restrict__ W,
          const float* __restrict__ bias, float* __restrict__ hid)
{
    __shared__ float xs[16 * 512];
    const int r0 = blockIdx.y * 16;
    const int c0 = blockIdx.x * 64;
    for (int i = threadIdx.x; i < 2048; i += 256)
        ((float4*)xs)[i] = ((const float4*)(xga + (size_t)r0 * 512))[i];
    __syncthreads();
    const int col = c0 + (threadIdx.x & 63);
    const int rg = (threadIdx.x >> 6) * 4;
    float acc[4] = {0.f, 0.f, 0.f, 0.f};
    const float4* w4 = (const float4*)(W + (size_t)col * 512);
    for (int k4 = 0; k4 < 128; ++k4) {
        float4 w = w4[k4];
#pragma unroll
        for (int rr = 0; rr < 4; ++rr) {
            float4 x = *(const float4*)&xs[(rg + rr) * 512 + k4 * 4];
            acc[rr] += w.x * x.x + w.y * x.y + w.z * x.z + w.w * x.w;
        }
    }
    const float bb = bias[col];
#pragma unroll
    for (int rr = 0; rr < 4; ++rr)
        hid[(size_t)(r0 + rg + rr) * 1024 + col] = fmaxf(acc[rr] + bb, 0.f);
}

__global__ __launch_bounds__(256)
void mlp2(const float* __restrict__ hid, const float* __restrict__ W,
          const float* __restrict__ bias, const float* __restrict__ xga,
          float* __restrict__ tex)
{
    __shared__ float xs[16 * 1024];
    const int r0 = blockIdx.y * 16;
    const int c0 = blockIdx.x * 64;
    for (int i = threadIdx.x; i < 4096; i += 256)
        ((float4*)xs)[i] = ((const float4*)(hid + (size_t)r0 * 1024))[i];
    __syncthreads();
    const int col = c0 + (threadIdx.x & 63);
    const int rg = (threadIdx.x >> 6) * 4;
    float acc[4] = {0.f, 0.f, 0.f, 0.f};
    const float4* w4 = (const float4*)(W + (size_t)col * 1024);
    for (int k4 = 0; k4 < 256; ++k4) {
        float4 w = w4[k4];
#pragma unroll
        for (int rr = 0; rr < 4; ++rr) {
            float4 x = *(const float4*)&xs[(rg + rr) * 1024 + k4 * 4];
            acc[rr] += w.x * x.x + w.y * x.y + w.z * x.z + w.w * x.w;
        }
    }
    const float bb = bias[col];
#pragma unroll
    for (int rr = 0; rr < 4; ++rr) {
        const int row = r0 + rg + rr;
        tex[(size_t)row * 512 + col] = acc[rr] + bb + xga[(size_t)row * 512 + col];
    }
}

__global__ __launch_bounds__(256)
void norm_out(const float* __restrict__ tex, float* __restrict__ out)
{
    __shared__ float red[256];
    const int b = blockIdx.x;
    const int t = threadIdx.x;
    const float a = tex[b * 512 + t];
    const float c = tex[b * 512 + 256 + t];
    red[t] = a * a + c * c;
    __syncthreads();
    for (int s = 128; s > 0; s >>= 1) {
        if (t < s) red[t] += red[t + s];
        __syncthreads();
    }
    const float inv = 1.f / (sqrtf(red[0]) + 1e-8f);
    out[b * 512 + t] = a * inv;
    out[b * 512 + 256 + t] = c * inv;
}

extern "C" void kernel_launch(void* const* d_in, const int* in_sizes, int n_in,
                              void* d_out, int out_size, void* d_ws, size_t ws_size,
                              hipStream_t stream)
{
    const float* cap = (const float*)d_in[0];
    const int* lengths = (const int*)d_in[1];
    const float* Wq  = (const float*)d_in[2];
    const float* Wk  = (const float*)d_in[3];
    const float* Wv  = (const float*)d_in[4];
    const float* bq  = (const float*)d_in[5];
    const float* bk  = (const float*)d_in[6];
    const float* bv  = (const float*)d_in[7];
    const float* Wfq = (const float*)d_in[8];
    const float* bfq = (const float*)d_in[9];
    const float* Wfk = (const float*)d_in[10];
    const float* bfk = (const float*)d_in[11];
    const float* Wfg = (const float*)d_in[12];
    const float* bfg = (const float*)d_in[13];
    const float* g1  = (const float*)d_in[14];
    const float* b1  = (const float*)d_in[15];
    const float* m1  = (const float*)d_in[16];
    const float* v1  = (const float*)d_in[17];
    const float* Wm1 = (const float*)d_in[30];
    const float* bm1 = (const float*)d_in[31];
    const float* Wm2 = (const float*)d_in[32];
    const float* bm2 = (const float*)d_in[33];
    float* out = (float*)d_out;

    char* w = (char*)d_ws;
    const size_t MB = 1024 * 1024;
    short* capB = (short*)(w);                 // 32MB bf16 cap (valid throughout)
    short* Kbuf = (short*)(w + 32 * MB);       // 32MB [32768,512] bf16
    short* Gbuf = (short*)(w + 64 * MB);       // 32MB [32768,512] bf16
    char* wp = w + 96 * MB;
    short* WkB   = (short*)wp; wp += 524288;   // [512,512]
    short* WaB   = (short*)wp; wp += 524288;   // [512,512] composed (rows h*256+o)
    short* WfkB  = (short*)wp; wp += 131072;
    short* Wfg2B = (short*)wp; wp += 131072;
    float* ba     = (float*)wp; wp += 2048;
    float* qg     = (float*)wp; wp += 262144;
    float* scorep = (float*)wp; wp += 524288;   // [128][2][256][2]
    float* pbar   = (float*)wp; wp += 524288;
    float* xga    = (float*)wp; wp += 262144;
    float* hid    = (float*)wp; wp += 524288;
    float* tex    = (float*)wp; wp += 262144;

    // 1. bf16 casts: cap, Wk, Wfk, Wfg2
    CastArgs ca;
    ca.src[0] = cap;          ca.dst[0] = capB;  ca.n4[0] = 4194304;
    ca.src[1] = Wk;           ca.dst[1] = WkB;   ca.n4[1] = 65536;
    ca.src[2] = Wfk;          ca.dst[2] = WfkB;  ca.n4[2] = 16384;
    ca.src[3] = Wfg + 65536;  ca.dst[3] = Wfg2B; ca.n4[3] = 16384;
    cast_multi<<<dim3(4096, 4), 256, 0, stream>>>(ca);

    // 2. composed Wa (bf16), ba
    compose<<<dim3(512), 256, 0, stream>>>(Wq, bq, Wfq, bfq, WaB, ba);

    // 3. K projection: 1-pass bf16
    gemm_k1<<<dim3(4, 256), 256, 0, stream>>>(capB, WkB, bk, Kbuf);

    // 4. G = (K_h Wfk^T + bfk) * (cap Wa_h^T + ba)  (dual K-loop) -> Gbuf
    gemm_g<<<dim3(2, 256, 2), 256, 0, stream>>>(Kbuf, capB, WfkB, WaB, bfk, ba, Gbuf);

    // 5. qg at gathered rows (Q fp32 from cap)
    qg_kernel<<<dim3(256), 256, 0, stream>>>(cap, Gbuf, Wq, bq, Wfg, bfg, lengths, qg);

    // 6. kg gemm + fused score partials
    gemm_kg<<<dim3(2, 256, 2), 256, 0, stream>>>(Gbuf, Wfg2B, bfg + 256, Kbuf, qg, scorep);

    // 7-8. softmax+pbar (bf16 cap), BN/residual
    pbar_kernel<<<dim3(8, 128), 256, 0, stream>>>(scorep, capB, pbar);
    bnx_kernel<<<dim3(128), 256, 0, stream>>>(pbar, cap, lengths, Wv, bv, g1, b1, m1, v1, xga);

    // 9-11. MLP, norm
    mlp1<<<dim3(16, 8), 256, 0, stream>>>(xga, Wm1, bm1, hid);
    mlp2<<<dim3(8, 8), 256, 0, stream>>>(hid, Wm2, bm2, xga, tex);
    norm_out<<<dim3(128), 256, 0, stream>>>(tex, out);
}

// Round 15
// 269.910 us; speedup vs baseline: 1.3218x; 1.0104x over previous
//
#include <hip/hip_runtime.h>
#include <math.h>

// BS=128, L=256, D=512, H=2, DK=256.
// Conv branches dead (gather idx < 256). ALL GEMMs 1-pass bf16 MFMA, 2-phase
// __syncthreads-only. floor(score/16)==sign(score) effectively; bf16 chain
// error safe under 4e-3 (measured 9.8e-4 last round). Compositions:
// A = Fq(Q(x)) -> Wa = Wfq@Wq_h;  Fk(K(x)) -> Wb = Wfk@Wk_h (gate-shielded).
// G = (cap@Wb^T+bb)*(cap@Wa^T+ba) single-A dual-B kernel. K never stored:
// computed fp32 inside kg's dual kloop. V GEMM removed via x=(p@cap)@Wv^T+bv.

typedef short bf16x8 __attribute__((ext_vector_type(8)));
typedef float f32x4 __attribute__((ext_vector_type(4)));
typedef short short4v __attribute__((ext_vector_type(4)));

__device__ __forceinline__ short f2bf(float x) {
    union { float f; unsigned u; } c; c.f = x;
    unsigned r = c.u + 0x7FFFu + ((c.u >> 16) & 1u);
    return (short)(r >> 16);
}
__device__ __forceinline__ float bf2f(short h) {
    union { float f; unsigned u; } c; c.u = ((unsigned)(unsigned short)h) << 16;
    return c.f;
}
__device__ __forceinline__ void glds16(const void* g, void* l) {
    __builtin_amdgcn_global_load_lds(
        (const __attribute__((address_space(1))) void*)g,
        (__attribute__((address_space(3))) void*)l, 16, 0, 0);
}

// ---------------- cast fp32 -> bf16 ----------------
struct CastArgs {
    const float* src[3];
    short* dst[3];
    int n4[3];
};
__global__ __launch_bounds__(256) void cast_multi(CastArgs a)
{
    const int j = blockIdx.y;
    const float4* s = (const float4*)a.src[j];
    short* d = a.dst[j];
    const int n4 = a.n4[j];
    for (int i = blockIdx.x * 256 + threadIdx.x; i < n4; i += gridDim.x * 256) {
        float4 x = s[i];
        short4v h;
        h.x = f2bf(x.x); h.y = f2bf(x.y); h.z = f2bf(x.z); h.w = f2bf(x.w);
        *(short4v*)&d[i * 4] = h;
    }
}

// ---------------- composed weights: W∘ = F @ W_h (bf16), b∘ = F@b_h + bf ----
// grid (512, 2): y=0 -> Wa from (Wq,bq,Wfq,bfq); y=1 -> Wb from (Wk,bk,Wfk,bfk)
__global__ __launch_bounds__(256)
void compose2(const float* __restrict__ Wq, const float* __restrict__ bq,
              const float* __restrict__ Wfq, const float* __restrict__ bfq,
              const float* __restrict__ Wk, const float* __restrict__ bk,
              const float* __restrict__ Wfk, const float* __restrict__ bfk,
              short* __restrict__ WaB, float* __restrict__ ba,
              short* __restrict__ WbB, float* __restrict__ bb)
{
    __shared__ float fq[256];
    __shared__ float redc[256];
    const int op = blockIdx.x;          // 0..511: h = op>>8, o = op&255
    const int h = op >> 8, o = op & 255;
    const int t = threadIdx.x;
    const bool second = (blockIdx.y == 1);
    const float* W  = second ? Wk  : Wq;
    const float* bv = second ? bk  : bq;
    const float* F  = second ? Wfk : Wfq;
    const float* bf = second ? bfk : bfq;
    short* WB   = second ? WbB : WaB;
    float* bout = second ? bb  : ba;

    fq[t] = F[o * 256 + t];
    redc[t] = fq[t] * bv[h * 256 + t];
    __syncthreads();
    for (int s = 128; s > 0; s >>= 1) {
        if (t < s) redc[t] += redc[t + s];
        __syncthreads();
    }
    if (t == 0) bout[op] = redc[0] + bf[o];
    float s0 = 0.f, s1 = 0.f;
    for (int d = 0; d < 256; ++d) {
        const float f = fq[d];
        const float* wr = W + (size_t)(h * 256 + d) * 512;
        s0 += f * wr[t];
        s1 += f * wr[t + 256];
    }
    const size_t ro = (size_t)op * 512;
    WB[ro + t] = f2bf(s0);
    WB[ro + 256 + t] = f2bf(s1);
}

// ---------------- shared 1-pass K-loop (2-phase, __syncthreads-only) ----------------
__device__ __forceinline__ void kloop_1p(
    const short* __restrict__ A, int lda,
    const short* __restrict__ B, int ldb,
    int K, int bm, int bn, short (*lds)[8192], int tid, f32x4 acc[4][4])
{
    const int lane = tid & 63;
    const int wr = (tid >> 7) & 1, wc = (tid >> 6) & 1;
    const int fr = lane & 15, kc = lane >> 4;
    const int r0 = tid >> 2;
    const int e0 = (((tid & 3) ^ ((r0 >> 1) & 3))) * 8;
    const int kce = (kc ^ ((fr >> 1) & 3)) * 8;

    auto stage = [&](int ph, int k0) {
        short* b = lds[ph];
        glds16(A + (size_t)(bm + r0) * lda + k0 + e0,      b + tid * 8);
        glds16(A + (size_t)(bm + r0 + 64) * lda + k0 + e0, b + (tid + 256) * 8);
        glds16(B + (size_t)(bn + r0) * ldb + k0 + e0,      b + 4096 + tid * 8);
        glds16(B + (size_t)(bn + r0 + 64) * ldb + k0 + e0, b + 4096 + (tid + 256) * 8);
    };

    stage(0, 0);
    __syncthreads();
    const int NS = K / 32;
    for (int s = 0; s < NS; ++s) {
        if (s + 1 < NS) stage((s + 1) & 1, (s + 1) * 32);
        const short* b = lds[s & 1];
        bf16x8 ah[4], bh[4];
#pragma unroll
        for (int i = 0; i < 4; ++i)
            ah[i] = *(const bf16x8*)&b[(wr * 64 + i * 16 + fr) * 32 + kce];
#pragma unroll
        for (int i = 0; i < 4; ++i)
            bh[i] = *(const bf16x8*)&b[4096 + (wc * 64 + i * 16 + fr) * 32 + kce];
#pragma unroll
        for (int mi = 0; mi < 4; ++mi)
#pragma unroll
            for (int ni = 0; ni < 4; ++ni)
                acc[mi][ni] = __builtin_amdgcn_mfma_f32_16x16x32_bf16(ah[mi], bh[ni], acc[mi][ni], 0, 0, 0);
        __syncthreads();
    }
}

// ---------------- G: single-A dual-B, G = (cap@Wb^T+bb)*(cap@Wa^T+ba) ----------------
__global__ __launch_bounds__(256, 2)
void gemm_g(const short* __restrict__ capB,
            const short* __restrict__ WaB, const short* __restrict__ WbB,
            const float* __restrict__ ba, const float* __restrict__ bb,
            short* __restrict__ Gbuf)
{
    __shared__ short lds[2][12288];   // A 8KB | B1 8KB | B2 8KB per phase
    const int tid = threadIdx.x;
    const int bm = blockIdx.y * 128;
    const int bn = blockIdx.x * 128;   // within-head col block
    const int z = blockIdx.z;
    const short* B1 = WaB + (size_t)z * 256 * 512;
    const short* B2 = WbB + (size_t)z * 256 * 512;

    const int lane = tid & 63;
    const int wr = (tid >> 7) & 1, wc = (tid >> 6) & 1;
    const int fr = lane & 15, kc = lane >> 4;
    const int r0 = tid >> 2;
    const int e0 = (((tid & 3) ^ ((r0 >> 1) & 3))) * 8;
    const int kce = (kc ^ ((fr >> 1) & 3)) * 8;

    auto stage = [&](int ph, int k0) {
        short* b = lds[ph];
        glds16(capB + (size_t)(bm + r0) * 512 + k0 + e0,      b + tid * 8);
        glds16(capB + (size_t)(bm + r0 + 64) * 512 + k0 + e0, b + (tid + 256) * 8);
        glds16(B1 + (size_t)(bn + r0) * 512 + k0 + e0,        b + 4096 + tid * 8);
        glds16(B1 + (size_t)(bn + r0 + 64) * 512 + k0 + e0,   b + 4096 + (tid + 256) * 8);
        glds16(B2 + (size_t)(bn + r0) * 512 + k0 + e0,        b + 8192 + tid * 8);
        glds16(B2 + (size_t)(bn + r0 + 64) * 512 + k0 + e0,   b + 8192 + (tid + 256) * 8);
    };

    f32x4 acc1[4][4], acc2[4][4];
#pragma unroll
    for (int i = 0; i < 4; ++i)
#pragma unroll
        for (int j = 0; j < 4; ++j) {
            acc1[i][j] = (f32x4){0.f, 0.f, 0.f, 0.f};
            acc2[i][j] = (f32x4){0.f, 0.f, 0.f, 0.f};
        }

    stage(0, 0);
    __syncthreads();
    for (int s = 0; s < 16; ++s) {
        if (s + 1 < 16) stage((s + 1) & 1, (s + 1) * 32);
        const short* b = lds[s & 1];
        bf16x8 ah[4], bh[4];
#pragma unroll
        for (int i = 0; i < 4; ++i)
            ah[i] = *(const bf16x8*)&b[(wr * 64 + i * 16 + fr) * 32 + kce];
#pragma unroll
        for (int i = 0; i < 4; ++i)
            bh[i] = *(const bf16x8*)&b[4096 + (wc * 64 + i * 16 + fr) * 32 + kce];
#pragma unroll
        for (int mi = 0; mi < 4; ++mi)
#pragma unroll
            for (int ni = 0; ni < 4; ++ni)
                acc1[mi][ni] = __builtin_amdgcn_mfma_f32_16x16x32_bf16(ah[mi], bh[ni], acc1[mi][ni], 0, 0, 0);
#pragma unroll
        for (int i = 0; i < 4; ++i)
            bh[i] = *(const bf16x8*)&b[8192 + (wc * 64 + i * 16 + fr) * 32 + kce];
#pragma unroll
        for (int mi = 0; mi < 4; ++mi)
#pragma unroll
            for (int ni = 0; ni < 4; ++ni)
                acc2[mi][ni] = __builtin_amdgcn_mfma_f32_16x16x32_bf16(ah[mi], bh[ni], acc2[mi][ni], 0, 0, 0);
        __syncthreads();
    }

#pragma unroll
    for (int mi = 0; mi < 4; ++mi) {
#pragma unroll
        for (int ni = 0; ni < 4; ++ni) {
#pragma unroll
            for (int r = 0; r < 4; ++r) {
                const int row = bm + wr * 64 + mi * 16 + kc * 4 + r;
                const int col = bn + wc * 64 + ni * 16 + fr;
                const float av  = acc1[mi][ni][r] + ba[z * 256 + col];
                const float lin = acc2[mi][ni][r] + bb[z * 256 + col];
                Gbuf[(size_t)row * 512 + z * 256 + col] = f2bf(lin * av);
            }
        }
    }
}

// ---------------- kg GEMM + in-kernel K + fused score partials ----------------
// acc1 = G_h @ Wfg2^T (K=256); acc2 = cap @ Wk_h^T (K=512, fp32 K in epilogue)
__global__ __launch_bounds__(256, 2)
void gemm_kg(const short* __restrict__ Gbuf,
             const short* __restrict__ Wfg2B, const float* __restrict__ bias,
             const short* __restrict__ capB,
             const short* __restrict__ WkB, const float* __restrict__ bk,
             const float* __restrict__ qg, float* __restrict__ scorep)
{
    __shared__ short lds[2][8192];
    __shared__ float sp[256];
    const int tid = threadIdx.x;
    const int bm = blockIdx.y * 128;
    const int bn = blockIdx.x * 128;
    const int z = blockIdx.z;

    f32x4 acc1[4][4], acc2[4][4];
#pragma unroll
    for (int i = 0; i < 4; ++i)
#pragma unroll
        for (int j = 0; j < 4; ++j) {
            acc1[i][j] = (f32x4){0.f, 0.f, 0.f, 0.f};
            acc2[i][j] = (f32x4){0.f, 0.f, 0.f, 0.f};
        }

    kloop_1p(Gbuf + (size_t)z * 256, 512, Wfg2B, 256, 256, bm, bn, lds, tid, acc1);
    kloop_1p(capB, 512, WkB + (size_t)z * 256 * 512, 512, 512, bm, bn, lds, tid, acc2);

    const int lane = tid & 63;
    const int wr = (tid >> 7) & 1, wc = (tid >> 6) & 1;
    const int fr = lane & 15, kc = lane >> 4;

    float qgv[4];
    float pt[4][4];
    {
        const int b = bm >> 8;
#pragma unroll
        for (int ni = 0; ni < 4; ++ni)
            qgv[ni] = qg[b * 512 + z * 256 + bn + wc * 64 + ni * 16 + fr];
#pragma unroll
        for (int mi = 0; mi < 4; ++mi)
#pragma unroll
            for (int r = 0; r < 4; ++r) pt[mi][r] = 0.f;
    }

#pragma unroll
    for (int mi = 0; mi < 4; ++mi) {
#pragma unroll
        for (int ni = 0; ni < 4; ++ni) {
#pragma unroll
            for (int r = 0; r < 4; ++r) {
                const int col = bn + wc * 64 + ni * 16 + fr;
                const float v = acc1[mi][ni][r] + bias[col];
                const float e = acc2[mi][ni][r] + bk[z * 256 + col];
                const float kgv = e / (1.f + expf(-v));
                pt[mi][r] += kgv * qgv[ni];
            }
        }
    }

#pragma unroll
    for (int mi = 0; mi < 4; ++mi) {
#pragma unroll
        for (int r = 0; r < 4; ++r) {
            float p = pt[mi][r];
            p += __shfl_xor(p, 1);
            p += __shfl_xor(p, 2);
            p += __shfl_xor(p, 4);
            p += __shfl_xor(p, 8);
            if (fr == 0) {
                const int row_local = wr * 64 + mi * 16 + kc * 4 + r;
                sp[row_local * 2 + wc] = p;
            }
        }
    }
    __syncthreads();
    if (tid < 128) {
        const int row = bm + tid;
        const float s = sp[tid * 2] + sp[tid * 2 + 1];
        const int b = row >> 8, j = row & 255;
        scorep[((size_t)(b * 2 + z) * 256 + j) * 2 + blockIdx.x] = s;
    }
}

// ---------------- qg at gathered rows: Q fp32-exact from cap ----------------
__global__ __launch_bounds__(256)
void qg_kernel(const float* __restrict__ cap,
               const short* __restrict__ Gbuf,
               const float* __restrict__ Wq, const float* __restrict__ bq,
               const float* __restrict__ Wfg, const float* __restrict__ bfg,
               const int* __restrict__ lengths, float* __restrict__ qg)
{
    __shared__ float cr[512];
    __shared__ float gs[256];
    const int b = blockIdx.x >> 1, h = blockIdx.x & 1;
    const int t = threadIdx.x;
    int r = lengths[b] - 1;
    if (r < 0) r = 0;
    if (r > 255) r = 255;
    const size_t base = ((size_t)b * 256 + r) * 512;
    cr[t] = cap[base + t];
    cr[t + 256] = cap[base + 256 + t];
    gs[t] = bf2f(Gbuf[base + h * 256 + t]);
    __syncthreads();
    const float4* wq4 = (const float4*)(Wq + (size_t)(h * 256 + t) * 512);
    float q = 0.f;
    for (int k4 = 0; k4 < 128; ++k4) {
        float4 w = wq4[k4];
        q += w.x * cr[k4 * 4 + 0] + w.y * cr[k4 * 4 + 1]
           + w.z * cr[k4 * 4 + 2] + w.w * cr[k4 * 4 + 3];
    }
    q += bq[h * 256 + t];
    const float4* w4 = (const float4*)(Wfg + (size_t)t * 256);
    float a = 0.f;
    for (int k4 = 0; k4 < 64; ++k4) {
        float4 w = w4[k4];
        a += w.x * gs[k4 * 4 + 0] + w.y * gs[k4 * 4 + 1]
           + w.z * gs[k4 * 4 + 2] + w.w * gs[k4 * 4 + 3];
    }
    a += bfg[t];
    qg[b * 512 + h * 256 + t] = q / (1.f + expf(-a));
}

// ---------------- softmax (inline) + pbar from bf16 cap ----------------
__global__ __launch_bounds__(256)
void pbar_kernel(const float* __restrict__ scorep, const short* __restrict__ capB,
                 float* __restrict__ pbar)
{
    __shared__ float sc[512], red[512];
    const int b = blockIdx.y, cg = blockIdx.x;
    const int t = threadIdx.x;
#pragma unroll
    for (int i = 0; i < 2; ++i) {
        const int o = t + i * 256;
        const int h = o >> 8, j = o & 255;
        const size_t si = ((size_t)(b * 2 + h) * 256 + j) * 2;
        sc[o] = floorf((scorep[si] + scorep[si + 1]) * 0.0625f);
    }
    __syncthreads();
    red[t] = sc[t]; red[t + 256] = sc[t + 256];
    __syncthreads();
    for (int s = 128; s > 0; s >>= 1) {
        if (t < s) {
            red[t] = fmaxf(red[t], red[t + s]);
            red[256 + t] = fmaxf(red[256 + t], red[256 + t + s]);
        }
        __syncthreads();
    }
    const float mx0 = red[0], mx1 = red[256];
    __syncthreads();
    const float e0 = expf(sc[t] - mx0);
    const float e1 = expf(sc[t + 256] - mx1);
    red[t] = e0; red[t + 256] = e1;
    __syncthreads();
    for (int s = 128; s > 0; s >>= 1) {
        if (t < s) { red[t] += red[t + s]; red[256 + t] += red[256 + t + s]; }
        __syncthreads();
    }
    sc[t] = e0 / red[0];
    sc[t + 256] = e1 / red[256];
    __syncthreads();

    const int c = cg * 64 + (t & 63);
    const int jg = t >> 6;
    float a0 = 0.f, a1 = 0.f;
    for (int j = jg * 64; j < jg * 64 + 64; ++j) {
        const float cv = bf2f(capB[((size_t)(b * 256 + j)) * 512 + c]);
        a0 += sc[j] * cv;
        a1 += sc[256 + j] * cv;
    }
    red[t] = a0;
    __syncthreads();
    if (t < 64) {
        const float s0 = red[t] + red[t + 64] + red[t + 128] + red[t + 192];
        pbar[b * 1024 + cg * 64 + t] = s0;
    }
    __syncthreads();
    red[t] = a1;
    __syncthreads();
    if (t < 64) {
        const float s1 = red[t] + red[t + 64] + red[t + 128] + red[t + 192];
        pbar[b * 1024 + 512 + cg * 64 + t] = s1;
    }
}

// ---------------- x = pbar@Wv^T + bv, BN1, residual ----------------
__global__ __launch_bounds__(256)
void bnx_kernel(const float* __restrict__ pbar, const float* __restrict__ cap,
                const int* __restrict__ lengths,
                const float* __restrict__ Wv, const float* __restrict__ bv,
                const float* __restrict__ g1, const float* __restrict__ b1,
                const float* __restrict__ m1, const float* __restrict__ v1,
                float* __restrict__ xga)
{
    __shared__ float pb[1024];
    const int b = blockIdx.x;
    const int t = threadIdx.x;
    int r = lengths[b] - 1;
    if (r < 0) r = 0;
    if (r > 255) r = 255;
    const size_t base = ((size_t)b * 256 + r) * 512;
    pb[t] = pbar[b * 1024 + t];
    pb[t + 256] = pbar[b * 1024 + 256 + t];
    pb[t + 512] = pbar[b * 1024 + 512 + t];
    pb[t + 768] = pbar[b * 1024 + 768 + t];
    __syncthreads();
    float x0 = 0.f, x1 = 0.f;
    {
        const float4* w4 = (const float4*)(Wv + (size_t)t * 512);
        for (int k4 = 0; k4 < 128; ++k4) {
            float4 w = w4[k4];
            x0 += w.x * pb[k4 * 4 + 0] + w.y * pb[k4 * 4 + 1]
                + w.z * pb[k4 * 4 + 2] + w.w * pb[k4 * 4 + 3];
        }
        x0 += bv[t];
    }
    {
        const float4* w4 = (const float4*)(Wv + (size_t)(t + 256) * 512);
        for (int k4 = 0; k4 < 128; ++k4) {
            float4 w = w4[k4];
            x1 += w.x * pb[512 + k4 * 4 + 0] + w.y * pb[512 + k4 * 4 + 1]
                + w.z * pb[512 + k4 * 4 + 2] + w.w * pb[512 + k4 * 4 + 3];
        }
        x1 += bv[t + 256];
    }
    const int c0 = t, c1 = t + 256;
    const float s0 = g1[c0] / sqrtf(v1[c0] + 1e-5f);
    const float s1 = g1[c1] / sqrtf(v1[c1] + 1e-5f);
    xga[b * 512 + c0] = cap[base + c0] + (x0 - m1[c0]) * s0 + b1[c0];
    xga[b * 512 + c1] = cap[base + c1] + (x1 - m1[c1]) * s1 + b1[c1];
}

// ---------------- MLP strip GEMMs (weights read once) ----------------
__global__ __launch_bounds__(256)
void mlp1(const float* __restrict__ xga, const float* __restrict__ W,
          const float* __restrict__ bias, float* __restrict__ hid)
{
    __shared__ float xs[16 * 512];
    const int r0 = blockIdx.y * 16;
    const int c0 = blockIdx.x * 64;
    for (int i = threadIdx.x; i < 2048; i += 256)
        ((float4*)xs)[i] = ((const float4*)(xga + (size_t)r0 * 512))[i];
    __syncthreads();
    const int col = c0 + (threadIdx.x & 63);
    const int rg = (threadIdx.x >> 6) * 4;
    float acc[4] = {0.f, 0.f, 0.f, 0.f};
    const float4* w4 = (const float4*)(W + (size_t)col * 512);
    for (int k4 = 0; k4 < 128; ++k4) {
        float4 w = w4[k4];
#pragma unroll
        for (int rr = 0; rr < 4; ++rr) {
            float4 x = *(const float4*)&xs[(rg + rr) * 512 + k4 * 4];
            acc[rr] += w.x * x.x + w.y * x.y + w.z * x.z + w.w * x.w;
        }
    }
    const float bb = bias[col];
#pragma unroll
    for (int rr = 0; rr < 4; ++rr)
        hid[(size_t)(r0 + rg + rr) * 1024 + col] = fmaxf(acc[rr] + bb, 0.f);
}

__global__ __launch_bounds__(256)
void mlp2(const float* __restrict__ hid, const float* __restrict__ W,
          const float* __restrict__ bias, const float* __restrict__ xga,
          float* __restrict__ tex)
{
    __shared__ float xs[16 * 1024];
    const int r0 = blockIdx.y * 16;
    const int c0 = blockIdx.x * 64;
    for (int i = threadIdx.x; i < 4096; i += 256)
        ((float4*)xs)[i] = ((const float4*)(hid + (size_t)r0 * 1024))[i];
    __syncthreads();
    const int col = c0 + (threadIdx.x & 63);
    const int rg = (threadIdx.x >> 6) * 4;
    float acc[4] = {0.f, 0.f, 0.f, 0.f};
    const float4* w4 = (const float4*)(W + (size_t)col * 1024);
    for (int k4 = 0; k4 < 256; ++k4) {
        float4 w = w4[k4];
#pragma unroll
        for (int rr = 0; rr < 4; ++rr) {
            float4 x = *(const float4*)&xs[(rg + rr) * 1024 + k4 * 4];
            acc[rr] += w.x * x.x + w.y * x.y + w.z * x.z + w.w * x.w;
        }
    }
    const float bb = bias[col];
#pragma unroll
    for (int rr = 0; rr < 4; ++rr) {
        const int row = r0 + rg + rr;
        tex[(size_t)row * 512 + col] = acc[rr] + bb + xga[(size_t)row * 512 + col];
    }
}

__global__ __launch_bounds__(256)
void norm_out(const float* __restrict__ tex, float* __restrict__ out)
{
    __shared__ float red[256];
    const int b = blockIdx.x;
    const int t = threadIdx.x;
    const float a = tex[b * 512 + t];
    const float c = tex[b * 512 + 256 + t];
    red[t] = a * a + c * c;
    __syncthreads();
    for (int s = 128; s > 0; s >>= 1) {
        if (t < s) red[t] += red[t + s];
        __syncthreads();
    }
    const float inv = 1.f / (sqrtf(red[0]) + 1e-8f);
    out[b * 512 + t] = a * inv;
    out[b * 512 + 256 + t] = c * inv;
}

extern "C" void kernel_launch(void* const* d_in, const int* in_sizes, int n_in,
                              void* d_out, int out_size, void* d_ws, size_t ws_size,
                              hipStream_t stream)
{
    const float* cap = (const float*)d_in[0];
    const int* lengths = (const int*)d_in[1];
    const float* Wq  = (const float*)d_in[2];
    const float* Wk  = (const float*)d_in[3];
    const float* Wv  = (const float*)d_in[4];
    const float* bq  = (const float*)d_in[5];
    const float* bk  = (const float*)d_in[6];
    const float* bv  = (const float*)d_in[7];
    const float* Wfq = (const float*)d_in[8];
    const float* bfq = (const float*)d_in[9];
    const float* Wfk = (const float*)d_in[10];
    const float* bfk = (const float*)d_in[11];
    const float* Wfg = (const float*)d_in[12];
    const float* bfg = (const float*)d_in[13];
    const float* g1  = (const float*)d_in[14];
    const float* b1  = (const float*)d_in[15];
    const float* m1  = (const float*)d_in[16];
    const float* v1  = (const float*)d_in[17];
    const float* Wm1 = (const float*)d_in[30];
    const float* bm1 = (const float*)d_in[31];
    const float* Wm2 = (const float*)d_in[32];
    const float* bm2 = (const float*)d_in[33];
    float* out = (float*)d_out;

    char* w = (char*)d_ws;
    const size_t MB = 1024 * 1024;
    short* capB = (short*)(w);                 // 32MB bf16 cap (valid throughout)
    short* Gbuf = (short*)(w + 32 * MB);       // 32MB [32768,512] bf16
    char* wp = w + 64 * MB;
    short* WkB   = (short*)wp; wp += 524288;   // [512,512] (kg's B)
    short* WaB   = (short*)wp; wp += 524288;   // composed Wfq@Wq_h
    short* WbB   = (short*)wp; wp += 524288;   // composed Wfk@Wk_h
    short* Wfg2B = (short*)wp; wp += 131072;
    float* ba     = (float*)wp; wp += 2048;
    float* bb     = (float*)wp; wp += 2048;
    float* qg     = (float*)wp; wp += 262144;
    float* scorep = (float*)wp; wp += 524288;   // [128][2][256][2]
    float* pbar   = (float*)wp; wp += 524288;
    float* xga    = (float*)wp; wp += 262144;
    float* hid    = (float*)wp; wp += 524288;
    float* tex    = (float*)wp; wp += 262144;

    // 1. bf16 casts: cap, Wk, Wfg2
    CastArgs ca;
    ca.src[0] = cap;          ca.dst[0] = capB;  ca.n4[0] = 4194304;
    ca.src[1] = Wk;           ca.dst[1] = WkB;   ca.n4[1] = 65536;
    ca.src[2] = Wfg + 65536;  ca.dst[2] = Wfg2B; ca.n4[2] = 16384;
    cast_multi<<<dim3(4096, 3), 256, 0, stream>>>(ca);

    // 2. composed Wa/ba and Wb/bb
    compose2<<<dim3(512, 2), 256, 0, stream>>>(Wq, bq, Wfq, bfq, Wk, bk, Wfk, bfk,
                                               WaB, ba, WbB, bb);

    // 3. G = (cap@Wb^T+bb)*(cap@Wa^T+ba)  (single-A dual-B) -> Gbuf
    gemm_g<<<dim3(2, 256, 2), 256, 0, stream>>>(capB, WaB, WbB, ba, bb, Gbuf);

    // 4. qg at gathered rows (Q fp32 from cap)
    qg_kernel<<<dim3(256), 256, 0, stream>>>(cap, Gbuf, Wq, bq, Wfg, bfg, lengths, qg);

    // 5. kg gemm + in-kernel K (fp32) + fused score partials
    gemm_kg<<<dim3(2, 256, 2), 256, 0, stream>>>(Gbuf, Wfg2B, bfg + 256,
                                                 capB, WkB, bk, qg, scorep);

    // 6-7. softmax+pbar (bf16 cap), BN/residual
    pbar_kernel<<<dim3(8, 128), 256, 0, stream>>>(scorep, capB, pbar);
    bnx_kernel<<<dim3(128), 256, 0, stream>>>(pbar, cap, lengths, Wv, bv, g1, b1, m1, v1, xga);

    // 8-10. MLP, norm
    mlp1<<<dim3(16, 8), 256, 0, stream>>>(xga, Wm1, bm1, hid);
    mlp2<<<dim3(8, 8), 256, 0, stream>>>(hid, Wm2, bm2, xga, tex);
    norm_out<<<dim3(128), 256, 0, stream>>>(tex, out);
}